// Round 11
// baseline (831.590 us; speedup 1.0000x reference)
//
#include <hip/hip_runtime.h>
#include <hip/hip_bf16.h>

// Problem constants
#define NN 32768      // nodes
#define BB 1024       // graphs
#define PP 32         // nodes per graph
#define EE 65536      // edges
#define HH 768
#define KSEM 1024
#define KCAT 1536
#define KP1 4608

typedef __attribute__((ext_vector_type(8))) short bf16x8;
typedef __attribute__((ext_vector_type(4))) float f32x4;

__device__ __forceinline__ unsigned short f2bf(float f){
  union { float f; unsigned u; } v; v.f = f;
  unsigned r = v.u + 0x7FFFu + ((v.u >> 16) & 1u);
  return (unsigned short)(r >> 16);
}
__device__ __forceinline__ float bf2f(unsigned short u){
  union { unsigned u; float f; } v; v.u = ((unsigned)u) << 16; return v.f;
}

__device__ __forceinline__ void gld_lds16(const void* g, void* l){
  __builtin_amdgcn_global_load_lds(
      (const __attribute__((address_space(1))) unsigned int*)g,
      (__attribute__((address_space(3))) unsigned int*)l, 16, 0, 0);
}

// ---------------- f32 -> bf16 cast, 8 elems/thread
__global__ __launch_bounds__(256) void k_cast(const float* __restrict__ in,
                                              unsigned short* __restrict__ out, int n8){
  int i = blockIdx.x * 256 + threadIdx.x;
  if (i >= n8) return;
  const float4* p = (const float4*)(in + (size_t)i * 8);
  float4 u0 = p[0], u1 = p[1];
  unsigned short vv[8];
  vv[0]=f2bf(u0.x); vv[1]=f2bf(u0.y); vv[2]=f2bf(u0.z); vv[3]=f2bf(u0.w);
  vv[4]=f2bf(u1.x); vv[5]=f2bf(u1.y); vv[6]=f2bf(u1.z); vv[7]=f2bf(u1.w);
  *(bf16x8*)(out + (size_t)i * 8) = *(bf16x8*)vv;
}

// ---------------- weight transpose: in (Kin x 768) f32 -> out[n*ostride + ooff + k] bf16
__global__ void k_transpose(const float* __restrict__ in, unsigned short* __restrict__ out,
                            int Kin, int ostride, int ooff){
  __shared__ float tile[32][33];
  int kb = blockIdx.x * 32, nb = blockIdx.y * 32;
  int tx = threadIdx.x & 31, ty = threadIdx.x >> 5; // 32 x 8
  #pragma unroll
  for (int i = ty; i < 32; i += 8)
    tile[i][tx] = in[(size_t)(kb + i) * 768 + nb + tx];
  __syncthreads();
  #pragma unroll
  for (int i = ty; i < 32; i += 8)
    out[(size_t)(nb + i) * ostride + ooff + kb + tx] = f2bf(tile[tx][i]);
}

// ================= 256x256 GEMM, m97-style 2-barrier loop, 64KB LDS = 2 blocks/CU =================
// C(M x 768) = A(M x K) @ B; A bf16 row-major [M][K], Bt = [768][K] bf16.
// 512 threads = 8 waves (2M x 4N); per-wave output 128x64; BK=64.
// SINGLE-buffered LDS (A 32KB @0, B 32KB @32768B) -> 2 blocks/CU co-resident;
// cross-block overlap (m114) hides the per-tile staging drain, replacing the
// 8-phase intra-block pipeline (which at 128KB was stuck at 1 block/CU and a
// 1.5-round grid imbalance -> 75% packing ceiling).
// st_16x32 swizzle unchanged: read byte ^= ((row>>2)&1)<<5; source pre-swizzled
// (valid for all 4 row-issues since the key depends on row mod 64 only).
// EPI 0: h_text = relu(acc + spk[sid]+emo[eid]) -> hb bf16, htext bf16
// EPI 1: h = relu(acc) + h (bf16 in place)

// load A frags for m-quadrant q (m = 2q, 2q+1), both k-slices
#define LDA(q) { _Pragma("unroll") for (int jj=0;jj<2;++jj){ \
    const int R_ = wrow*128 + ((q)*2+jj)*16 + l15; const int sw_ = ((R_>>2)&1)<<5; \
    af[jj][0] = *(const bf16x8*)((const char*)LDS + R_*128 + ((kq)^sw_)); \
    af[jj][1] = *(const bf16x8*)((const char*)LDS + R_*128 + ((64+kq)^sw_)); }}
// load all 4 B frags (n=0..3), both k-slices (once per K-tile, reused across 4 quadrants)
#define LDB() { _Pragma("unroll") for (int nn=0;nn<4;++nn){ \
    const int R_ = wcol*64 + nn*16 + l15; const int sw_ = ((R_>>2)&1)<<5; \
    bfr[nn][0] = *(const bf16x8*)((const char*)LDS + 32768 + R_*128 + ((kq)^sw_)); \
    bfr[nn][1] = *(const bf16x8*)((const char*)LDS + 32768 + R_*128 + ((64+kq)^sw_)); }}
#define MMA(q) { __builtin_amdgcn_s_setprio(1); \
    _Pragma("unroll") for (int jj=0;jj<2;++jj) _Pragma("unroll") for (int nn=0;nn<4;++nn){ \
      acc[(q)*2+jj][nn] = __builtin_amdgcn_mfma_f32_16x16x32_bf16(af[jj][0], bfr[nn][0], acc[(q)*2+jj][nn],0,0,0); \
      acc[(q)*2+jj][nn] = __builtin_amdgcn_mfma_f32_16x16x32_bf16(af[jj][1], bfr[nn][1], acc[(q)*2+jj][nn],0,0,0); } \
    __builtin_amdgcn_s_setprio(0); }

template<int EPI>
__global__ __launch_bounds__(512, 2) void k_gemm8(
    const unsigned short* __restrict__ A, const unsigned short* __restrict__ Bt, int K,
    unsigned short* __restrict__ hb, unsigned short* __restrict__ htext,
    const int* __restrict__ sid, const int* __restrict__ eid,
    const float* __restrict__ spk, const float* __restrict__ emo)
{
  __shared__ unsigned short LDS[32768];   // 64 KiB: A shorts [0,16384), B [16384,32768)
  const int t = threadIdx.x;
  const int lane = t & 63, w = t >> 6;
  const int wrow = w >> 2, wcol = w & 3;

  // bijective XCD-chunked swizzle (gridDim.x % 8 == 0), col-fastest (3 col panels)
  const int bid = blockIdx.x;
  const int cpx = gridDim.x >> 3;
  const int wg = (bid & 7) * cpx + (bid >> 3);
  const int by = wg / 3, bx = wg - by * 3;
  const int brow = by * 256, bcol = bx * 256;

  f32x4 acc[8][4];
  #pragma unroll
  for (int m = 0; m < 8; ++m)
    #pragma unroll
    for (int n = 0; n < 4; ++n) acc[m][n] = f32x4{0.f,0.f,0.f,0.f};

  // staging: thread t covers row (t>>3) of each 64-row issue, cols 8*(t&7)..+8,
  // with source column pre-swizzled so linear LDS ends up st_16x32-swizzled.
  const int srow = t >> 3;
  const int scol = ((t & 7) * 8) ^ (((t >> 5) & 1) << 4);
  const unsigned short* aS = A  + (size_t)(brow + srow) * K + scol;
  const unsigned short* bS = Bt + (size_t)(bcol + srow) * K + scol;
  unsigned short* dA = LDS + (size_t)w * 512;   // wave-uniform base + lane*16B
  unsigned short* dB = dA + 16384;
  const int l15 = lane & 15, kq = (lane >> 4) * 16;  // kq in bytes
  const int nkt = K >> 6;

  bf16x8 af[2][2], bfr[4][2];

  for (int kt = 0; kt < nkt; ++kt){
    {
      const unsigned short* s_ = aS + (size_t)kt * 64;
      gld_lds16(s_,                   dA);
      gld_lds16(s_ + (size_t)64*K,    dA + 4096);
      gld_lds16(s_ + (size_t)128*K,   dA + 8192);
      gld_lds16(s_ + (size_t)192*K,   dA + 12288);
    }
    {
      const unsigned short* s_ = bS + (size_t)kt * 64;
      gld_lds16(s_,                   dB);
      gld_lds16(s_ + (size_t)64*K,    dB + 4096);
      gld_lds16(s_ + (size_t)128*K,   dB + 8192);
      gld_lds16(s_ + (size_t)192*K,   dB + 12288);
    }
    __syncthreads();   // compiler emits vmcnt(0) drain; co-resident block overlaps it
    LDA(0); LDB(); MMA(0);
    LDA(1);        MMA(1);
    LDA(2);        MMA(2);
    LDA(3);        MMA(3);
    __syncthreads();   // reads done before next tile's staging overwrites
  }

  // epilogue: C/D layout col=lane&15, row=(lane>>4)*4+reg
  #pragma unroll
  for (int m = 0; m < 8; ++m){
    #pragma unroll
    for (int n = 0; n < 4; ++n){
      const int col = bcol + wcol*64 + n*16 + l15;
      #pragma unroll
      for (int j = 0; j < 4; ++j){
        const int row = brow + wrow*128 + m*16 + ((lane>>4)*4) + j;
        float v = acc[m][n][j];
        if (EPI == 0){
          float e = spk[sid[row] * 768 + col] + emo[eid[row] * 768 + col];
          v = fmaxf(v + e, 0.f);
          const unsigned short b = f2bf(v);
          hb[(size_t)row * 768 + col] = b;
          htext[(size_t)row * 768 + col] = b;
        } else {
          v = fmaxf(v, 0.f) + bf2f(hb[(size_t)row * 768 + col]);
          hb[(size_t)row * 768 + col] = f2bf(v);
        }
      }
    }
  }
}

// ================= 128x128 m97-style GEMM for the small (M=1024) shapes =================
// EPI 2: z = relu(acc + bias) -> obf at col base 3840, stride 4608 (edge_repr)
// EPI 3: hid = relu(acc + bias) -> of32 stride 768
template<int EPI>
__global__ __launch_bounds__(256) void k_gemm(
    const unsigned short* __restrict__ A, const unsigned short* __restrict__ Bt, int K,
    const float* __restrict__ bias,
    unsigned short* __restrict__ obf, float* __restrict__ of32)
{
  __shared__ unsigned short As[128*64];
  __shared__ unsigned short Bs[128*64];
  const int t = threadIdx.x;
  const int lane = t & 63, wave = t >> 6;

  const int bid = blockIdx.x;
  const int cpx = gridDim.x >> 3;
  const int wg = (bid & 7) * cpx + (bid >> 3);
  const int by = wg / 6;
  const int bx = wg - by * 6;
  const int brow = by * 128;
  const int bcol = bx * 128;

  const int wr = (wave >> 1) * 64, wc = (wave & 1) * 64;

  f32x4 acc[4][4];
  #pragma unroll
  for (int m = 0; m < 4; ++m)
    #pragma unroll
    for (int n = 0; n < 4; ++n)
      acc[m][n] = f32x4{0.f, 0.f, 0.f, 0.f};

  const int srow = wave * 8 + (lane >> 3);
  const int scol = (lane & 7) * 8;
  const int nkt = K >> 6;

  const unsigned short* a0 = A  + (size_t)(brow + srow) * K + scol;
  const unsigned short* b0 = Bt + (size_t)(bcol + srow) * K + scol;
  unsigned short* asdst = As + wave * 512;
  unsigned short* bsdst = Bs + wave * 512;

  for (int kt = 0; kt < nkt; ++kt){
    const unsigned short* ak = a0 + kt * 64;
    const unsigned short* bk = b0 + kt * 64;
    #pragma unroll
    for (int i = 0; i < 4; ++i)
      gld_lds16(ak + (size_t)i * 32 * K, asdst + i * 2048);
    #pragma unroll
    for (int i = 0; i < 4; ++i)
      gld_lds16(bk + (size_t)i * 32 * K, bsdst + i * 2048);
    __syncthreads();

    #pragma unroll
    for (int ks = 0; ks < 2; ++ks){
      bf16x8 af[4], bfr[4];
      const int kb = ks * 64 + ((lane >> 4) * 16);
      #pragma unroll
      for (int m = 0; m < 4; ++m)
        af[m] = *(const bf16x8*)((const char*)As + (wr + m * 16 + (lane & 15)) * 128 + kb);
      #pragma unroll
      for (int n = 0; n < 4; ++n)
        bfr[n] = *(const bf16x8*)((const char*)Bs + (wc + n * 16 + (lane & 15)) * 128 + kb);
      #pragma unroll
      for (int m = 0; m < 4; ++m)
        #pragma unroll
        for (int n = 0; n < 4; ++n)
          acc[m][n] = __builtin_amdgcn_mfma_f32_16x16x32_bf16(af[m], bfr[n], acc[m][n], 0, 0, 0);
    }
    __syncthreads();
  }

  #pragma unroll
  for (int m = 0; m < 4; ++m){
    #pragma unroll
    for (int n = 0; n < 4; ++n){
      int col = bcol + wc + n * 16 + (lane & 15);
      #pragma unroll
      for (int j = 0; j < 4; ++j){
        int row = brow + wr + m * 16 + ((lane >> 4) * 4) + j;
        float v = acc[m][n][j];
        if (EPI == 2){
          v = fmaxf(v + bias[col], 0.f);
          obf[(size_t)row * 4608 + 3840 + col] = f2bf(v);
        } else {
          v = fmaxf(v + bias[col], 0.f);
          of32[(size_t)row * 768 + col] = v;
        }
      }
    }
  }
}

// ---------------- per-graph segment sum + build bf16 [h | msg] A-buffer
// Source is bf16 hb: stage 48KB via bf16x8 copies, sum from LDS.
__global__ __launch_bounds__(256) void k_scatter(const unsigned short* __restrict__ hb,
                                                 const int* __restrict__ esrc,
                                                 const int* __restrict__ etgt,
                                                 unsigned short* __restrict__ acat){
  __shared__ unsigned short hsm[32 * 768];   // 48KB
  __shared__ int cnt[32];
  __shared__ unsigned char lst[32][64];
  const int g = blockIdx.x, t = threadIdx.x;
  const unsigned short* src = hb + (size_t)g * 32 * 768;
  #pragma unroll
  for (int i = 0; i < 12; ++i){
    const int o = (i * 256 + t) * 8;
    *(bf16x8*)(hsm + o) = *(const bf16x8*)(src + o);
  }
  if (t < 32) cnt[t] = 0;
  __syncthreads();
  if (t < 64){
    const int e = g * 64 + t;
    const int s = esrc[e] & 31, tg = etgt[e] & 31;   // intra-graph local ids
    const int slot = atomicAdd(&cnt[tg], 1);
    lst[tg][slot] = (unsigned char)s;
  }
  __syncthreads();
  for (int n = 0; n < 32; ++n){
    float s0 = 0.f, s1 = 0.f, s2 = 0.f;
    const int c = cnt[n];
    for (int e = 0; e < c; ++e){
      const unsigned short* r = hsm + (int)lst[n][e] * 768;
      s0 += bf2f(r[t]); s1 += bf2f(r[t + 256]); s2 += bf2f(r[t + 512]);
    }
    unsigned short* oa = acat + (size_t)(g * 32 + n) * 1536;
    const unsigned short* hr = hsm + n * 768;
    oa[t]       = hr[t];
    oa[t + 256] = hr[t + 256];
    oa[t + 512] = hr[t + 512];
    oa[768 + t]       = f2bf(s0);
    oa[768 + t + 256] = f2bf(s1);
    oa[768 + t + 512] = f2bf(s2);
  }
}

// ---------------- per-graph: dist + gather h_c/h_t/h_dist into edge_repr
__global__ __launch_bounds__(256) void k_build(const unsigned short* __restrict__ hb,
                                               const unsigned short* __restrict__ htext,
                                               const int* __restrict__ tni,
                                               const int* __restrict__ esrc,
                                               const int* __restrict__ etgt,
                                               const float* __restrict__ dist_emb,
                                               unsigned short* __restrict__ er){
  int g = blockIdx.x;
  int t = threadIdx.x;
  __shared__ int s_dist;
  int c = tni[g * 2 + 0], tt = tni[g * 2 + 1];
  if (t == 0){
    // reference quirk: first_edge indexed with LOCAL node ids -> graph 0's edges only
    int cu = c, tu = tt;
    for (int e = 0; e < 64; ++e){ if (esrc[e] == c){ cu = etgt[e]; break; } }
    for (int e = 0; e < 64; ++e){ if (esrc[e] == tt){ tu = etgt[e]; break; } }
    int d = cu - tu; if (d < 0) d = -d; if (d > 31) d = 31;
    s_dist = d;
  }
  __syncthreads();
  size_t rc = (size_t)(g * 32 + c) * 768, rt = (size_t)(g * 32 + tt) * 768;
  unsigned short* o = er + (size_t)g * 4608;
  int d = s_dist;
  for (int i = t; i < 768; i += 256){
    o[i]        = hb[rc + i];
    o[768 + i]  = htext[rc + i];
    o[1536 + i] = hb[rt + i];
    o[2304 + i] = htext[rt + i];
    o[3072 + i] = f2bf(dist_emb[(size_t)d * 768 + i]);
  }
}

// ---------------- logits: out[i] = hid[i,:] . W_p2 + b_p2
__global__ __launch_bounds__(256) void k_logits(const float* __restrict__ hid,
                                                const float* __restrict__ wp2,
                                                const float* __restrict__ bp2,
                                                float* __restrict__ out){
  int row = blockIdx.x * 4 + (threadIdx.x >> 6);
  int lane = threadIdx.x & 63;
  const float* r = hid + (size_t)row * 768;
  float s = 0.f;
  for (int j = lane; j < 768; j += 64) s += r[j] * wp2[j];
  #pragma unroll
  for (int off = 32; off; off >>= 1) s += __shfl_down(s, off);
  if (lane == 0) out[row] = s + bp2[0];
}

extern "C" void kernel_launch(void* const* d_in, const int* in_sizes, int n_in,
                              void* d_out, int out_size, void* d_ws, size_t ws_size,
                              hipStream_t stream){
  const float* x        = (const float*)d_in[0];
  const int*   sid      = (const int*)d_in[1];
  const int*   eid      = (const int*)d_in[2];
  const int*   esrc     = (const int*)d_in[3];
  const int*   etgt     = esrc + EE;
  const int*   tni      = (const int*)d_in[4];
  const float* expl     = (const float*)d_in[5];
  const float* W_sem    = (const float*)d_in[6];
  const float* spk      = (const float*)d_in[7];
  const float* emo      = (const float*)d_in[8];
  const float* w_self   = (const float*)d_in[9];
  const float* w_nbr    = (const float*)d_in[10];
  const float* dist_emb = (const float*)d_in[11];
  const float* W_expl   = (const float*)d_in[12];
  const float* b_expl   = (const float*)d_in[13];
  const float* W_p1     = (const float*)d_in[14];
  const float* b_p1     = (const float*)d_in[15];
  const float* W_p2     = (const float*)d_in[16];
  const float* b_p2     = (const float*)d_in[17];

  char* ws = (char*)d_ws;
  size_t off = 0;
  auto alloc = [&](size_t bytes) -> void* {
    void* p = ws + off; off += (bytes + 255) & ~(size_t)255; return p;
  };
  unsigned short* hb    = (unsigned short*)alloc((size_t)NN * HH * 2);
  unsigned short* htext = (unsigned short*)alloc((size_t)NN * HH * 2);
  unsigned short* acat  = (unsigned short*)alloc((size_t)NN * KCAT * 2);
  unsigned short* WsemT = (unsigned short*)alloc((size_t)HH * KSEM * 2);
  unsigned short* WcatT = (unsigned short*)alloc((size_t)3 * HH * KCAT * 2);
  unsigned short* WexplT= (unsigned short*)alloc((size_t)HH * HH * 2);
  unsigned short* Wp1T  = (unsigned short*)alloc((size_t)HH * KP1 * 2);
  unsigned short* erepr = (unsigned short*)alloc((size_t)BB * KP1 * 2);
  float*          hid   = (float*)alloc((size_t)BB * HH * 4);
  unsigned short* explbf= (unsigned short*)alloc((size_t)BB * HH * 2);
  // xbf aliases acat: only live until sem GEMM completes; acat first written after.
  unsigned short* xbf   = acat;
  (void)ws_size; (void)in_sizes; (void)n_in; (void)out_size;

  // weight transposes (f32 -> bf16, [K][768] -> [768][K])
  k_transpose<<<dim3(KSEM/32, 24), 256, 0, stream>>>(W_sem, WsemT, KSEM, KSEM, 0);
  for (int l = 0; l < 3; ++l){
    k_transpose<<<dim3(24, 24), 256, 0, stream>>>(w_self + (size_t)l*HH*HH, WcatT + (size_t)l*HH*KCAT, HH, KCAT, 0);
    k_transpose<<<dim3(24, 24), 256, 0, stream>>>(w_nbr  + (size_t)l*HH*HH, WcatT + (size_t)l*HH*KCAT, HH, KCAT, HH);
  }
  k_transpose<<<dim3(24, 24), 256, 0, stream>>>(W_expl, WexplT, HH, HH, 0);
  k_transpose<<<dim3(KP1/32, 24), 256, 0, stream>>>(W_p1, Wp1T, KP1, KP1, 0);

  // activation casts f32 -> bf16
  k_cast<<<(NN*KSEM/8 + 255)/256, 256, 0, stream>>>(x, xbf, NN*KSEM/8);
  k_cast<<<(BB*HH/8 + 255)/256, 256, 0, stream>>>(expl, explbf, BB*HH/8);

  // h_text = relu(x @ W_sem + spk + emo)  [256^2, 2 blocks/CU]
  k_gemm8<0><<<3*(NN/256), 512, 0, stream>>>(xbf, WsemT, KSEM,
      hb, htext, sid, eid, spk, emo);

  // 3 GNN layers  [256^2, 2 blocks/CU]
  for (int l = 0; l < 3; ++l){
    k_scatter<<<BB, 256, 0, stream>>>(hb, esrc, etgt, acat);
    k_gemm8<1><<<3*(NN/256), 512, 0, stream>>>(acat, WcatT + (size_t)l*HH*KCAT, KCAT,
        hb, nullptr, nullptr, nullptr, nullptr, nullptr);
  }

  // z_teacher into edge_repr cols [3840,4608)  [128^2]
  k_gemm<2><<<6*(BB/128), 256, 0, stream>>>(explbf, WexplT, HH, b_expl, erepr, nullptr);

  // gather h_c/h_t/h_dist into edge_repr cols [0,3840)
  k_build<<<BB, 256, 0, stream>>>(hb, htext, tni, esrc, etgt, dist_emb, erepr);

  // hid = relu(edge_repr @ W_p1 + b_p1)  [128^2]
  k_gemm<3><<<6*(BB/128), 256, 0, stream>>>(erepr, Wp1T, KP1, b_p1, nullptr, hid);

  // logits
  k_logits<<<BB/4, 256, 0, stream>>>(hid, W_p2, b_p2, (float*)d_out);
}

// Round 12
// 644.998 us; speedup vs baseline: 1.2893x; 1.2893x over previous
//
#include <hip/hip_runtime.h>
#include <hip/hip_bf16.h>

// Problem constants
#define NN 32768      // nodes
#define BB 1024       // graphs
#define PP 32         // nodes per graph
#define EE 65536      // edges
#define HH 768
#define KSEM 1024
#define KCAT 1536
#define KP1 4608

typedef __attribute__((ext_vector_type(8))) short bf16x8;
typedef __attribute__((ext_vector_type(4))) float f32x4;

__device__ __forceinline__ unsigned short f2bf(float f){
  union { float f; unsigned u; } v; v.f = f;
  unsigned r = v.u + 0x7FFFu + ((v.u >> 16) & 1u);
  return (unsigned short)(r >> 16);
}
__device__ __forceinline__ float bf2f(unsigned short u){
  union { unsigned u; float f; } v; v.u = ((unsigned)u) << 16; return v.f;
}

__device__ __forceinline__ void gld_lds16(const void* g, void* l){
  __builtin_amdgcn_global_load_lds(
      (const __attribute__((address_space(1))) unsigned int*)g,
      (__attribute__((address_space(3))) unsigned int*)l, 16, 0, 0);
}

// ---------------- f32 -> bf16 cast, 8 elems/thread
__global__ __launch_bounds__(256) void k_cast(const float* __restrict__ in,
                                              unsigned short* __restrict__ out, int n8){
  int i = blockIdx.x * 256 + threadIdx.x;
  if (i >= n8) return;
  const float4* p = (const float4*)(in + (size_t)i * 8);
  float4 u0 = p[0], u1 = p[1];
  unsigned short vv[8];
  vv[0]=f2bf(u0.x); vv[1]=f2bf(u0.y); vv[2]=f2bf(u0.z); vv[3]=f2bf(u0.w);
  vv[4]=f2bf(u1.x); vv[5]=f2bf(u1.y); vv[6]=f2bf(u1.z); vv[7]=f2bf(u1.w);
  *(bf16x8*)(out + (size_t)i * 8) = *(bf16x8*)vv;
}

// ---------------- weight transpose: in (Kin x 768) f32 -> out[n*ostride + ooff + k] bf16
__global__ void k_transpose(const float* __restrict__ in, unsigned short* __restrict__ out,
                            int Kin, int ostride, int ooff){
  __shared__ float tile[32][33];
  int kb = blockIdx.x * 32, nb = blockIdx.y * 32;
  int tx = threadIdx.x & 31, ty = threadIdx.x >> 5; // 32 x 8
  #pragma unroll
  for (int i = ty; i < 32; i += 8)
    tile[i][tx] = in[(size_t)(kb + i) * 768 + nb + tx];
  __syncthreads();
  #pragma unroll
  for (int i = ty; i < 32; i += 8)
    out[(size_t)(nb + i) * ostride + ooff + kb + tx] = f2bf(tile[tx][i]);
}

// ================= 256x192 8-phase GEMM (R10 schedule, BN 256->192) =================
// C(M x 768) = A(M x K) @ B; A bf16 row-major [M][K], Bt = [768][K] bf16.
// 512 threads = 8 waves (2M x 4N); per-wave output 128x48; BK=64.
// Grid = (M/256)*4 = 512 blocks = EXACTLY 2 full rounds at 1 block/CU
// (R10's 384 blocks = 1.5 rounds cost 2 round-times; same rounds, 0.75x work).
// LDS 112KB: A dbuf 2x32KB @0, B dbuf 2x24KB @65536B.
// st_16x32 swizzle unchanged: read byte ^= ((row>>2)&1)<<5; source pre-swizzled.
// vmcnt(3) at tile boundaries: in-flight = next-A(4) + nextnext-B(3); wait
// leaves B's 3 flying (never drains to 0 in-loop).
// EPI 0: h_text = relu(acc + spk[sid]+emo[eid]) -> hb bf16, htext bf16
// EPI 1: h = relu(acc) + h (bf16 in place)

#define BAR __builtin_amdgcn_s_barrier()
#define WAITL asm volatile("s_waitcnt lgkmcnt(0)" ::: "memory")
#define WAITV3 asm volatile("s_waitcnt vmcnt(3)" ::: "memory")
#define WAITV0 asm volatile("s_waitcnt vmcnt(0)" ::: "memory")

// stage A half-tile (128 rows x 64 cols = 16KB) = 2 gld_lds per thread
#define STG_A(buf,half,tile) { const unsigned short* s_ = aS + (size_t)((half)*128)*K + (tile)*64; \
    gld_lds16(s_,                 dA + (buf)*16384 + (half)*8192); \
    gld_lds16(s_ + (size_t)64*K,  dA + (buf)*16384 + (half)*8192 + 4096); }
// stage B third-tile (64 rows x 64 cols = 8KB) = 1 gld_lds per thread
#define STG_B1(buf,third,tile) { const unsigned short* s_ = bS + (size_t)((third)*64)*K + (tile)*64; \
    gld_lds16(s_, dB + (buf)*12288 + (third)*4096); }
// load A frags for m-quadrant q (m = 2q, 2q+1), both k-slices
#define LDA(buf,q) { _Pragma("unroll") for (int jj=0;jj<2;++jj){ \
    const int R_ = wrow*128 + ((q)*2+jj)*16 + l15; const int sw_ = ((R_>>2)&1)<<5; \
    af[jj][0] = *(const bf16x8*)((const char*)LDS + (buf)*32768 + R_*128 + ((kq)^sw_)); \
    af[jj][1] = *(const bf16x8*)((const char*)LDS + (buf)*32768 + R_*128 + ((64+kq)^sw_)); }}
// load all 3 B frags (n=0..2), both k-slices (once per K-tile, reused across 4 phases)
#define LDB(buf) { _Pragma("unroll") for (int nn=0;nn<3;++nn){ \
    const int R_ = wcol*48 + nn*16 + l15; const int sw_ = ((R_>>2)&1)<<5; \
    bfr[nn][0] = *(const bf16x8*)((const char*)LDS + 65536 + (buf)*24576 + R_*128 + ((kq)^sw_)); \
    bfr[nn][1] = *(const bf16x8*)((const char*)LDS + 65536 + (buf)*24576 + R_*128 + ((64+kq)^sw_)); }}
#define MMA(q) { __builtin_amdgcn_s_setprio(1); \
    _Pragma("unroll") for (int jj=0;jj<2;++jj) _Pragma("unroll") for (int nn=0;nn<3;++nn){ \
      acc[(q)*2+jj][nn] = __builtin_amdgcn_mfma_f32_16x16x32_bf16(af[jj][0], bfr[nn][0], acc[(q)*2+jj][nn],0,0,0); \
      acc[(q)*2+jj][nn] = __builtin_amdgcn_mfma_f32_16x16x32_bf16(af[jj][1], bfr[nn][1], acc[(q)*2+jj][nn],0,0,0); } \
    __builtin_amdgcn_s_setprio(0); }

template<int EPI>
__global__ __launch_bounds__(512, 2) void k_gemm8(
    const unsigned short* __restrict__ A, const unsigned short* __restrict__ Bt, int K,
    unsigned short* __restrict__ hb, unsigned short* __restrict__ htext,
    const int* __restrict__ sid, const int* __restrict__ eid,
    const float* __restrict__ spk, const float* __restrict__ emo)
{
  __shared__ unsigned short LDS[57344];   // 112 KiB: A [0,32768) shorts, B [32768,57344)
  const int t = threadIdx.x;
  const int lane = t & 63, w = t >> 6;
  const int wrow = w >> 2, wcol = w & 3;

  // bijective XCD-chunked swizzle (gridDim.x % 8 == 0), col-fastest (4 col panels)
  const int bid = blockIdx.x;
  const int cpx = gridDim.x >> 3;
  const int wg = (bid & 7) * cpx + (bid >> 3);
  const int by = wg >> 2, bx = wg & 3;
  const int brow = by * 256, bcol = bx * 192;

  f32x4 acc[8][3];
  #pragma unroll
  for (int m = 0; m < 8; ++m)
    #pragma unroll
    for (int n = 0; n < 3; ++n) acc[m][n] = f32x4{0.f,0.f,0.f,0.f};

  // staging: thread t covers row (t>>3) of a 64-row issue, cols 8*(t&7)..+8,
  // with source column pre-swizzled so linear LDS ends up st_16x32-swizzled.
  const int srow = t >> 3;
  const int scol = ((t & 7) * 8) ^ (((t >> 5) & 1) << 4);
  const unsigned short* aS = A  + (size_t)(brow + srow) * K + scol;
  const unsigned short* bS = Bt + (size_t)(bcol + srow) * K + scol;
  unsigned short* dA = LDS + (size_t)w * 512;
  unsigned short* dB = LDS + 32768 + (size_t)w * 512;
  const int l15 = lane & 15, kq = (lane >> 4) * 16;  // kq in bytes
  const int nkt = K >> 6, niter = nkt >> 1;

  bf16x8 af[2][2], bfr[3][2];

  // prologue: B(0) x3, A(0) x4, B(1) x3; wait tile0's 7, leave B(1)'s 3 flying
  STG_B1(0,0,0); STG_B1(0,1,0); STG_B1(0,2,0);
  STG_A(0,0,0);  STG_A(0,1,0);
  STG_B1(1,0,1); STG_B1(1,1,1); STG_B1(1,2,1);
  WAITV3;
  BAR;

  for (int i = 0; i < niter; ++i){
    const int t1 = 2*i+1;
    const int t2 = (2*i+2 < nkt) ? 2*i+2 : nkt-1;   // tail: re-fetch valid tile, data unused
    const int t3 = (2*i+3 < nkt) ? 2*i+3 : nkt-1;
    // ---- tile 2i from buf0 ----
    LDA(0,0); LDB(0); STG_A(1,0,t1);                 // buf1.A freed at prev ph8
    BAR; WAITL; MMA(0); BAR;                         // ph1
    LDA(0,1);         STG_A(1,1,t1);
    BAR; WAITL; MMA(1); BAR;                         // ph2
    LDA(0,2);         STG_B1(0,0,t2); STG_B1(0,1,t2); // buf0.B freed at ph1
    BAR; WAITL; MMA(2); BAR;                         // ph3
    LDA(0,3);         STG_B1(0,2,t2);
    BAR; WAITL; MMA(3);
    WAITV3; BAR;                                     // ph4: A(t1)+B(t1) landed (leaves B(t2) x3)
    // ---- tile 2i+1 from buf1 ----
    LDA(1,0); LDB(1); STG_A(0,0,t2);                 // buf0.A freed at ph4
    BAR; WAITL; MMA(0); BAR;                         // ph5
    LDA(1,1);         STG_A(0,1,t2);
    BAR; WAITL; MMA(1); BAR;                         // ph6
    LDA(1,2);         STG_B1(1,0,t3); STG_B1(1,1,t3); // buf1.B freed at ph5
    BAR; WAITL; MMA(2); BAR;                         // ph7
    LDA(1,3);         STG_B1(1,2,t3);
    BAR; WAITL; MMA(3);
    WAITV3; BAR;                                     // ph8: A(t2)+B(t2) landed (leaves B(t3) x3)
  }
  WAITV0;  // drain tail prefetches before exit

  // epilogue: C/D layout col=lane&15, row=(lane>>4)*4+reg
  #pragma unroll
  for (int m = 0; m < 8; ++m){
    #pragma unroll
    for (int n = 0; n < 3; ++n){
      const int col = bcol + wcol*48 + n*16 + l15;
      #pragma unroll
      for (int j = 0; j < 4; ++j){
        const int row = brow + wrow*128 + m*16 + ((lane>>4)*4) + j;
        float v = acc[m][n][j];
        if (EPI == 0){
          float e = spk[sid[row] * 768 + col] + emo[eid[row] * 768 + col];
          v = fmaxf(v + e, 0.f);
          const unsigned short b = f2bf(v);
          hb[(size_t)row * 768 + col] = b;
          htext[(size_t)row * 768 + col] = b;
        } else {
          v = fmaxf(v, 0.f) + bf2f(hb[(size_t)row * 768 + col]);
          hb[(size_t)row * 768 + col] = f2bf(v);
        }
      }
    }
  }
}

// ================= 128x128 m97-style GEMM for the small (M=1024) shapes =================
// EPI 2: z = relu(acc + bias) -> obf at col base 3840, stride 4608 (edge_repr)
// EPI 3: hid = relu(acc + bias) -> of32 stride 768
template<int EPI>
__global__ __launch_bounds__(256) void k_gemm(
    const unsigned short* __restrict__ A, const unsigned short* __restrict__ Bt, int K,
    const float* __restrict__ bias,
    unsigned short* __restrict__ obf, float* __restrict__ of32)
{
  __shared__ unsigned short As[128*64];
  __shared__ unsigned short Bs[128*64];
  const int t = threadIdx.x;
  const int lane = t & 63, wave = t >> 6;

  const int bid = blockIdx.x;
  const int cpx = gridDim.x >> 3;
  const int wg = (bid & 7) * cpx + (bid >> 3);
  const int by = wg / 6;
  const int bx = wg - by * 6;
  const int brow = by * 128;
  const int bcol = bx * 128;

  const int wr = (wave >> 1) * 64, wc = (wave & 1) * 64;

  f32x4 acc[4][4];
  #pragma unroll
  for (int m = 0; m < 4; ++m)
    #pragma unroll
    for (int n = 0; n < 4; ++n)
      acc[m][n] = f32x4{0.f, 0.f, 0.f, 0.f};

  const int srow = wave * 8 + (lane >> 3);
  const int scol = (lane & 7) * 8;
  const int nkt = K >> 6;

  const unsigned short* a0 = A  + (size_t)(brow + srow) * K + scol;
  const unsigned short* b0 = Bt + (size_t)(bcol + srow) * K + scol;
  unsigned short* asdst = As + wave * 512;
  unsigned short* bsdst = Bs + wave * 512;

  for (int kt = 0; kt < nkt; ++kt){
    const unsigned short* ak = a0 + kt * 64;
    const unsigned short* bk = b0 + kt * 64;
    #pragma unroll
    for (int i = 0; i < 4; ++i)
      gld_lds16(ak + (size_t)i * 32 * K, asdst + i * 2048);
    #pragma unroll
    for (int i = 0; i < 4; ++i)
      gld_lds16(bk + (size_t)i * 32 * K, bsdst + i * 2048);
    __syncthreads();

    #pragma unroll
    for (int ks = 0; ks < 2; ++ks){
      bf16x8 af[4], bfr[4];
      const int kb = ks * 64 + ((lane >> 4) * 16);
      #pragma unroll
      for (int m = 0; m < 4; ++m)
        af[m] = *(const bf16x8*)((const char*)As + (wr + m * 16 + (lane & 15)) * 128 + kb);
      #pragma unroll
      for (int n = 0; n < 4; ++n)
        bfr[n] = *(const bf16x8*)((const char*)Bs + (wc + n * 16 + (lane & 15)) * 128 + kb);
      #pragma unroll
      for (int m = 0; m < 4; ++m)
        #pragma unroll
        for (int n = 0; n < 4; ++n)
          acc[m][n] = __builtin_amdgcn_mfma_f32_16x16x32_bf16(af[m], bfr[n], acc[m][n], 0, 0, 0);
    }
    __syncthreads();
  }

  #pragma unroll
  for (int m = 0; m < 4; ++m){
    #pragma unroll
    for (int n = 0; n < 4; ++n){
      int col = bcol + wc + n * 16 + (lane & 15);
      #pragma unroll
      for (int j = 0; j < 4; ++j){
        int row = brow + wr + m * 16 + ((lane >> 4) * 4) + j;
        float v = acc[m][n][j];
        if (EPI == 2){
          v = fmaxf(v + bias[col], 0.f);
          obf[(size_t)row * 4608 + 3840 + col] = f2bf(v);
        } else {
          v = fmaxf(v + bias[col], 0.f);
          of32[(size_t)row * 768 + col] = v;
        }
      }
    }
  }
}

// ---------------- per-graph segment sum + build bf16 [h | msg] A-buffer
// Source is bf16 hb: stage 48KB via bf16x8 copies, sum from LDS.
__global__ __launch_bounds__(256) void k_scatter(const unsigned short* __restrict__ hb,
                                                 const int* __restrict__ esrc,
                                                 const int* __restrict__ etgt,
                                                 unsigned short* __restrict__ acat){
  __shared__ unsigned short hsm[32 * 768];   // 48KB
  __shared__ int cnt[32];
  __shared__ unsigned char lst[32][64];
  const int g = blockIdx.x, t = threadIdx.x;
  const unsigned short* src = hb + (size_t)g * 32 * 768;
  #pragma unroll
  for (int i = 0; i < 12; ++i){
    const int o = (i * 256 + t) * 8;
    *(bf16x8*)(hsm + o) = *(const bf16x8*)(src + o);
  }
  if (t < 32) cnt[t] = 0;
  __syncthreads();
  if (t < 64){
    const int e = g * 64 + t;
    const int s = esrc[e] & 31, tg = etgt[e] & 31;   // intra-graph local ids
    const int slot = atomicAdd(&cnt[tg], 1);
    lst[tg][slot] = (unsigned char)s;
  }
  __syncthreads();
  for (int n = 0; n < 32; ++n){
    float s0 = 0.f, s1 = 0.f, s2 = 0.f;
    const int c = cnt[n];
    for (int e = 0; e < c; ++e){
      const unsigned short* r = hsm + (int)lst[n][e] * 768;
      s0 += bf2f(r[t]); s1 += bf2f(r[t + 256]); s2 += bf2f(r[t + 512]);
    }
    unsigned short* oa = acat + (size_t)(g * 32 + n) * 1536;
    const unsigned short* hr = hsm + n * 768;
    oa[t]       = hr[t];
    oa[t + 256] = hr[t + 256];
    oa[t + 512] = hr[t + 512];
    oa[768 + t]       = f2bf(s0);
    oa[768 + t + 256] = f2bf(s1);
    oa[768 + t + 512] = f2bf(s2);
  }
}

// ---------------- per-graph: dist + gather h_c/h_t/h_dist into edge_repr
__global__ __launch_bounds__(256) void k_build(const unsigned short* __restrict__ hb,
                                               const unsigned short* __restrict__ htext,
                                               const int* __restrict__ tni,
                                               const int* __restrict__ esrc,
                                               const int* __restrict__ etgt,
                                               const float* __restrict__ dist_emb,
                                               unsigned short* __restrict__ er){
  int g = blockIdx.x;
  int t = threadIdx.x;
  __shared__ int s_dist;
  int c = tni[g * 2 + 0], tt = tni[g * 2 + 1];
  if (t == 0){
    // reference quirk: first_edge indexed with LOCAL node ids -> graph 0's edges only
    int cu = c, tu = tt;
    for (int e = 0; e < 64; ++e){ if (esrc[e] == c){ cu = etgt[e]; break; } }
    for (int e = 0; e < 64; ++e){ if (esrc[e] == tt){ tu = etgt[e]; break; } }
    int d = cu - tu; if (d < 0) d = -d; if (d > 31) d = 31;
    s_dist = d;
  }
  __syncthreads();
  size_t rc = (size_t)(g * 32 + c) * 768, rt = (size_t)(g * 32 + tt) * 768;
  unsigned short* o = er + (size_t)g * 4608;
  int d = s_dist;
  for (int i = t; i < 768; i += 256){
    o[i]        = hb[rc + i];
    o[768 + i]  = htext[rc + i];
    o[1536 + i] = hb[rt + i];
    o[2304 + i] = htext[rt + i];
    o[3072 + i] = f2bf(dist_emb[(size_t)d * 768 + i]);
  }
}

// ---------------- logits: out[i] = hid[i,:] . W_p2 + b_p2
__global__ __launch_bounds__(256) void k_logits(const float* __restrict__ hid,
                                                const float* __restrict__ wp2,
                                                const float* __restrict__ bp2,
                                                float* __restrict__ out){
  int row = blockIdx.x * 4 + (threadIdx.x >> 6);
  int lane = threadIdx.x & 63;
  const float* r = hid + (size_t)row * 768;
  float s = 0.f;
  for (int j = lane; j < 768; j += 64) s += r[j] * wp2[j];
  #pragma unroll
  for (int off = 32; off; off >>= 1) s += __shfl_down(s, off);
  if (lane == 0) out[row] = s + bp2[0];
}

extern "C" void kernel_launch(void* const* d_in, const int* in_sizes, int n_in,
                              void* d_out, int out_size, void* d_ws, size_t ws_size,
                              hipStream_t stream){
  const float* x        = (const float*)d_in[0];
  const int*   sid      = (const int*)d_in[1];
  const int*   eid      = (const int*)d_in[2];
  const int*   esrc     = (const int*)d_in[3];
  const int*   etgt     = esrc + EE;
  const int*   tni      = (const int*)d_in[4];
  const float* expl     = (const float*)d_in[5];
  const float* W_sem    = (const float*)d_in[6];
  const float* spk      = (const float*)d_in[7];
  const float* emo      = (const float*)d_in[8];
  const float* w_self   = (const float*)d_in[9];
  const float* w_nbr    = (const float*)d_in[10];
  const float* dist_emb = (const float*)d_in[11];
  const float* W_expl   = (const float*)d_in[12];
  const float* b_expl   = (const float*)d_in[13];
  const float* W_p1     = (const float*)d_in[14];
  const float* b_p1     = (const float*)d_in[15];
  const float* W_p2     = (const float*)d_in[16];
  const float* b_p2     = (const float*)d_in[17];

  char* ws = (char*)d_ws;
  size_t off = 0;
  auto alloc = [&](size_t bytes) -> void* {
    void* p = ws + off; off += (bytes + 255) & ~(size_t)255; return p;
  };
  unsigned short* hb    = (unsigned short*)alloc((size_t)NN * HH * 2);
  unsigned short* htext = (unsigned short*)alloc((size_t)NN * HH * 2);
  unsigned short* acat  = (unsigned short*)alloc((size_t)NN * KCAT * 2);
  unsigned short* WsemT = (unsigned short*)alloc((size_t)HH * KSEM * 2);
  unsigned short* WcatT = (unsigned short*)alloc((size_t)3 * HH * KCAT * 2);
  unsigned short* WexplT= (unsigned short*)alloc((size_t)HH * HH * 2);
  unsigned short* Wp1T  = (unsigned short*)alloc((size_t)HH * KP1 * 2);
  unsigned short* erepr = (unsigned short*)alloc((size_t)BB * KP1 * 2);
  float*          hid   = (float*)alloc((size_t)BB * HH * 4);
  unsigned short* explbf= (unsigned short*)alloc((size_t)BB * HH * 2);
  // xbf aliases acat: only live until sem GEMM completes; acat first written after.
  unsigned short* xbf   = acat;
  (void)ws_size; (void)in_sizes; (void)n_in; (void)out_size;

  // weight transposes (f32 -> bf16, [K][768] -> [768][K])
  k_transpose<<<dim3(KSEM/32, 24), 256, 0, stream>>>(W_sem, WsemT, KSEM, KSEM, 0);
  for (int l = 0; l < 3; ++l){
    k_transpose<<<dim3(24, 24), 256, 0, stream>>>(w_self + (size_t)l*HH*HH, WcatT + (size_t)l*HH*KCAT, HH, KCAT, 0);
    k_transpose<<<dim3(24, 24), 256, 0, stream>>>(w_nbr  + (size_t)l*HH*HH, WcatT + (size_t)l*HH*KCAT, HH, KCAT, HH);
  }
  k_transpose<<<dim3(24, 24), 256, 0, stream>>>(W_expl, WexplT, HH, HH, 0);
  k_transpose<<<dim3(KP1/32, 24), 256, 0, stream>>>(W_p1, Wp1T, KP1, KP1, 0);

  // activation casts f32 -> bf16
  k_cast<<<(NN*KSEM/8 + 255)/256, 256, 0, stream>>>(x, xbf, NN*KSEM/8);
  k_cast<<<(BB*HH/8 + 255)/256, 256, 0, stream>>>(expl, explbf, BB*HH/8);

  // h_text = relu(x @ W_sem + spk + emo)  [256x192 8-phase, 512 blocks = 2 exact rounds]
  k_gemm8<0><<<4*(NN/256), 512, 0, stream>>>(xbf, WsemT, KSEM,
      hb, htext, sid, eid, spk, emo);

  // 3 GNN layers  [256x192 8-phase]
  for (int l = 0; l < 3; ++l){
    k_scatter<<<BB, 256, 0, stream>>>(hb, esrc, etgt, acat);
    k_gemm8<1><<<4*(NN/256), 512, 0, stream>>>(acat, WcatT + (size_t)l*HH*KCAT, KCAT,
        hb, nullptr, nullptr, nullptr, nullptr, nullptr);
  }

  // z_teacher into edge_repr cols [3840,4608)  [128^2]
  k_gemm<2><<<6*(BB/128), 256, 0, stream>>>(explbf, WexplT, HH, b_expl, erepr, nullptr);

  // gather h_c/h_t/h_dist into edge_repr cols [0,3840)
  k_build<<<BB, 256, 0, stream>>>(hb, htext, tni, esrc, etgt, dist_emb, erepr);

  // hid = relu(edge_repr @ W_p1 + b_p1)  [128^2]
  k_gemm<3><<<6*(BB/128), 256, 0, stream>>>(erepr, Wp1T, KP1, b_p1, nullptr, hid);

  // logits
  k_logits<<<BB/4, 256, 0, stream>>>(hid, W_p2, b_p2, (float*)d_out);
}

// Round 13
// 567.537 us; speedup vs baseline: 1.4653x; 1.1365x over previous
//
#include <hip/hip_runtime.h>
#include <hip/hip_bf16.h>

// Problem constants
#define NN 32768      // nodes
#define BB 1024       // graphs
#define PP 32         // nodes per graph
#define EE 65536      // edges
#define HH 768
#define KSEM 1024
#define KCAT 1536
#define KP1 4608

typedef __attribute__((ext_vector_type(8))) short bf16x8;
typedef __attribute__((ext_vector_type(4))) float f32x4;

__device__ __forceinline__ unsigned short f2bf(float f){
  union { float f; unsigned u; } v; v.f = f;
  unsigned r = v.u + 0x7FFFu + ((v.u >> 16) & 1u);
  return (unsigned short)(r >> 16);
}
__device__ __forceinline__ float bf2f(unsigned short u){
  union { unsigned u; float f; } v; v.u = ((unsigned)u) << 16; return v.f;
}

__device__ __forceinline__ void gld_lds16(const void* g, void* l){
  __builtin_amdgcn_global_load_lds(
      (const __attribute__((address_space(1))) unsigned int*)g,
      (__attribute__((address_space(3))) unsigned int*)l, 16, 0, 0);
}

// ---------------- f32 -> bf16 cast, 8 elems/thread
__global__ __launch_bounds__(256) void k_cast(const float* __restrict__ in,
                                              unsigned short* __restrict__ out, int n8){
  int i = blockIdx.x * 256 + threadIdx.x;
  if (i >= n8) return;
  const float4* p = (const float4*)(in + (size_t)i * 8);
  float4 u0 = p[0], u1 = p[1];
  unsigned short vv[8];
  vv[0]=f2bf(u0.x); vv[1]=f2bf(u0.y); vv[2]=f2bf(u0.z); vv[3]=f2bf(u0.w);
  vv[4]=f2bf(u1.x); vv[5]=f2bf(u1.y); vv[6]=f2bf(u1.z); vv[7]=f2bf(u1.w);
  *(bf16x8*)(out + (size_t)i * 8) = *(bf16x8*)vv;
}

// ---------------- weight transpose: in (Kin x 768) f32 -> out[n*ostride + ooff + k] bf16
__global__ void k_transpose(const float* __restrict__ in, unsigned short* __restrict__ out,
                            int Kin, int ostride, int ooff){
  __shared__ float tile[32][33];
  int kb = blockIdx.x * 32, nb = blockIdx.y * 32;
  int tx = threadIdx.x & 31, ty = threadIdx.x >> 5; // 32 x 8
  #pragma unroll
  for (int i = ty; i < 32; i += 8)
    tile[i][tx] = in[(size_t)(kb + i) * 768 + nb + tx];
  __syncthreads();
  #pragma unroll
  for (int i = ty; i < 32; i += 8)
    out[(size_t)(nb + i) * ostride + ooff + kb + tx] = f2bf(tile[tx][i]);
}

// ================= 256x192 8-phase GEMM (R12, FROZEN) =================
// C(M x 768) = A(M x K) @ B; A bf16 row-major [M][K], Bt = [768][K] bf16.
// 512 threads = 8 waves (2M x 4N); per-wave output 128x48; BK=64.
// Grid = (M/256)*4 = 512 blocks = EXACTLY 2 full rounds at 1 block/CU.
// LDS 112KB: A dbuf 2x32KB @0, B dbuf 2x24KB @65536B.
// st_16x32 swizzle: read byte ^= ((row>>2)&1)<<5; source pre-swizzled.
// vmcnt(3) at tile boundaries (leaves next-B's 3 loads flying).
// EPI 0: h_text = relu(acc + spk[sid]+emo[eid]) -> hb bf16, htext bf16
// EPI 1: h = relu(acc) + h (bf16 in place)

#define BAR __builtin_amdgcn_s_barrier()
#define WAITL asm volatile("s_waitcnt lgkmcnt(0)" ::: "memory")
#define WAITV3 asm volatile("s_waitcnt vmcnt(3)" ::: "memory")
#define WAITV0 asm volatile("s_waitcnt vmcnt(0)" ::: "memory")

// stage A half-tile (128 rows x 64 cols = 16KB) = 2 gld_lds per thread
#define STG_A(buf,half,tile) { const unsigned short* s_ = aS + (size_t)((half)*128)*K + (tile)*64; \
    gld_lds16(s_,                 dA + (buf)*16384 + (half)*8192); \
    gld_lds16(s_ + (size_t)64*K,  dA + (buf)*16384 + (half)*8192 + 4096); }
// stage B third-tile (64 rows x 64 cols = 8KB) = 1 gld_lds per thread
#define STG_B1(buf,third,tile) { const unsigned short* s_ = bS + (size_t)((third)*64)*K + (tile)*64; \
    gld_lds16(s_, dB + (buf)*12288 + (third)*4096); }
// load A frags for m-quadrant q (m = 2q, 2q+1), both k-slices
#define LDA(buf,q) { _Pragma("unroll") for (int jj=0;jj<2;++jj){ \
    const int R_ = wrow*128 + ((q)*2+jj)*16 + l15; const int sw_ = ((R_>>2)&1)<<5; \
    af[jj][0] = *(const bf16x8*)((const char*)LDS + (buf)*32768 + R_*128 + ((kq)^sw_)); \
    af[jj][1] = *(const bf16x8*)((const char*)LDS + (buf)*32768 + R_*128 + ((64+kq)^sw_)); }}
// load all 3 B frags (n=0..2), both k-slices (once per K-tile, reused across 4 phases)
#define LDB(buf) { _Pragma("unroll") for (int nn=0;nn<3;++nn){ \
    const int R_ = wcol*48 + nn*16 + l15; const int sw_ = ((R_>>2)&1)<<5; \
    bfr[nn][0] = *(const bf16x8*)((const char*)LDS + 65536 + (buf)*24576 + R_*128 + ((kq)^sw_)); \
    bfr[nn][1] = *(const bf16x8*)((const char*)LDS + 65536 + (buf)*24576 + R_*128 + ((64+kq)^sw_)); }}
#define MMA(q) { __builtin_amdgcn_s_setprio(1); \
    _Pragma("unroll") for (int jj=0;jj<2;++jj) _Pragma("unroll") for (int nn=0;nn<3;++nn){ \
      acc[(q)*2+jj][nn] = __builtin_amdgcn_mfma_f32_16x16x32_bf16(af[jj][0], bfr[nn][0], acc[(q)*2+jj][nn],0,0,0); \
      acc[(q)*2+jj][nn] = __builtin_amdgcn_mfma_f32_16x16x32_bf16(af[jj][1], bfr[nn][1], acc[(q)*2+jj][nn],0,0,0); } \
    __builtin_amdgcn_s_setprio(0); }

template<int EPI>
__global__ __launch_bounds__(512, 2) void k_gemm8(
    const unsigned short* __restrict__ A, const unsigned short* __restrict__ Bt, int K,
    unsigned short* __restrict__ hb, unsigned short* __restrict__ htext,
    const int* __restrict__ sid, const int* __restrict__ eid,
    const float* __restrict__ spk, const float* __restrict__ emo)
{
  __shared__ unsigned short LDS[57344];   // 112 KiB: A [0,32768) shorts, B [32768,57344)
  const int t = threadIdx.x;
  const int lane = t & 63, w = t >> 6;
  const int wrow = w >> 2, wcol = w & 3;

  // bijective XCD-chunked swizzle (gridDim.x % 8 == 0), col-fastest (4 col panels)
  const int bid = blockIdx.x;
  const int cpx = gridDim.x >> 3;
  const int wg = (bid & 7) * cpx + (bid >> 3);
  const int by = wg >> 2, bx = wg & 3;
  const int brow = by * 256, bcol = bx * 192;

  f32x4 acc[8][3];
  #pragma unroll
  for (int m = 0; m < 8; ++m)
    #pragma unroll
    for (int n = 0; n < 3; ++n) acc[m][n] = f32x4{0.f,0.f,0.f,0.f};

  // staging: thread t covers row (t>>3) of a 64-row issue, cols 8*(t&7)..+8,
  // with source column pre-swizzled so linear LDS ends up st_16x32-swizzled.
  const int srow = t >> 3;
  const int scol = ((t & 7) * 8) ^ (((t >> 5) & 1) << 4);
  const unsigned short* aS = A  + (size_t)(brow + srow) * K + scol;
  const unsigned short* bS = Bt + (size_t)(bcol + srow) * K + scol;
  unsigned short* dA = LDS + (size_t)w * 512;
  unsigned short* dB = LDS + 32768 + (size_t)w * 512;
  const int l15 = lane & 15, kq = (lane >> 4) * 16;  // kq in bytes
  const int nkt = K >> 6, niter = nkt >> 1;

  bf16x8 af[2][2], bfr[3][2];

  // prologue: B(0) x3, A(0) x4, B(1) x3; wait tile0's 7, leave B(1)'s 3 flying
  STG_B1(0,0,0); STG_B1(0,1,0); STG_B1(0,2,0);
  STG_A(0,0,0);  STG_A(0,1,0);
  STG_B1(1,0,1); STG_B1(1,1,1); STG_B1(1,2,1);
  WAITV3;
  BAR;

  for (int i = 0; i < niter; ++i){
    const int t1 = 2*i+1;
    const int t2 = (2*i+2 < nkt) ? 2*i+2 : nkt-1;   // tail: re-fetch valid tile, data unused
    const int t3 = (2*i+3 < nkt) ? 2*i+3 : nkt-1;
    // ---- tile 2i from buf0 ----
    LDA(0,0); LDB(0); STG_A(1,0,t1);                 // buf1.A freed at prev ph8
    BAR; WAITL; MMA(0); BAR;                         // ph1
    LDA(0,1);         STG_A(1,1,t1);
    BAR; WAITL; MMA(1); BAR;                         // ph2
    LDA(0,2);         STG_B1(0,0,t2); STG_B1(0,1,t2); // buf0.B freed at ph1
    BAR; WAITL; MMA(2); BAR;                         // ph3
    LDA(0,3);         STG_B1(0,2,t2);
    BAR; WAITL; MMA(3);
    WAITV3; BAR;                                     // ph4: A(t1)+B(t1) landed (leaves B(t2) x3)
    // ---- tile 2i+1 from buf1 ----
    LDA(1,0); LDB(1); STG_A(0,0,t2);                 // buf0.A freed at ph4
    BAR; WAITL; MMA(0); BAR;                         // ph5
    LDA(1,1);         STG_A(0,1,t2);
    BAR; WAITL; MMA(1); BAR;                         // ph6
    LDA(1,2);         STG_B1(1,0,t3); STG_B1(1,1,t3); // buf1.B freed at ph5
    BAR; WAITL; MMA(2); BAR;                         // ph7
    LDA(1,3);         STG_B1(1,2,t3);
    BAR; WAITL; MMA(3);
    WAITV3; BAR;                                     // ph8: A(t2)+B(t2) landed (leaves B(t3) x3)
  }
  WAITV0;  // drain tail prefetches before exit

  // epilogue: C/D layout col=lane&15, row=(lane>>4)*4+reg
  #pragma unroll
  for (int m = 0; m < 8; ++m){
    #pragma unroll
    for (int n = 0; n < 3; ++n){
      const int col = bcol + wcol*48 + n*16 + l15;
      #pragma unroll
      for (int j = 0; j < 4; ++j){
        const int row = brow + wrow*128 + m*16 + ((lane>>4)*4) + j;
        float v = acc[m][n][j];
        if (EPI == 0){
          float e = spk[sid[row] * 768 + col] + emo[eid[row] * 768 + col];
          v = fmaxf(v + e, 0.f);
          const unsigned short b = f2bf(v);
          hb[(size_t)row * 768 + col] = b;
          htext[(size_t)row * 768 + col] = b;
        } else {
          v = fmaxf(v, 0.f) + bf2f(hb[(size_t)row * 768 + col]);
          hb[(size_t)row * 768 + col] = f2bf(v);
        }
      }
    }
  }
}

// ================= 128x128 m97-style GEMM (z_teacher only) =================
// EPI 2: z = relu(acc + bias) -> obf at col base 3840, stride 4608 (edge_repr)
template<int EPI>
__global__ __launch_bounds__(256) void k_gemm(
    const unsigned short* __restrict__ A, const unsigned short* __restrict__ Bt, int K,
    const float* __restrict__ bias,
    unsigned short* __restrict__ obf, float* __restrict__ of32)
{
  __shared__ unsigned short As[128*64];
  __shared__ unsigned short Bs[128*64];
  const int t = threadIdx.x;
  const int lane = t & 63, wave = t >> 6;

  const int bid = blockIdx.x;
  const int cpx = gridDim.x >> 3;
  const int wg = (bid & 7) * cpx + (bid >> 3);
  const int by = wg / 6;
  const int bx = wg - by * 6;
  const int brow = by * 128;
  const int bcol = bx * 128;

  const int wr = (wave >> 1) * 64, wc = (wave & 1) * 64;

  f32x4 acc[4][4];
  #pragma unroll
  for (int m = 0; m < 4; ++m)
    #pragma unroll
    for (int n = 0; n < 4; ++n)
      acc[m][n] = f32x4{0.f, 0.f, 0.f, 0.f};

  const int srow = wave * 8 + (lane >> 3);
  const int scol = (lane & 7) * 8;
  const int nkt = K >> 6;

  const unsigned short* a0 = A  + (size_t)(brow + srow) * K + scol;
  const unsigned short* b0 = Bt + (size_t)(bcol + srow) * K + scol;
  unsigned short* asdst = As + wave * 512;
  unsigned short* bsdst = Bs + wave * 512;

  for (int kt = 0; kt < nkt; ++kt){
    const unsigned short* ak = a0 + kt * 64;
    const unsigned short* bk = b0 + kt * 64;
    #pragma unroll
    for (int i = 0; i < 4; ++i)
      gld_lds16(ak + (size_t)i * 32 * K, asdst + i * 2048);
    #pragma unroll
    for (int i = 0; i < 4; ++i)
      gld_lds16(bk + (size_t)i * 32 * K, bsdst + i * 2048);
    __syncthreads();

    #pragma unroll
    for (int ks = 0; ks < 2; ++ks){
      bf16x8 af[4], bfr[4];
      const int kb = ks * 64 + ((lane >> 4) * 16);
      #pragma unroll
      for (int m = 0; m < 4; ++m)
        af[m] = *(const bf16x8*)((const char*)As + (wr + m * 16 + (lane & 15)) * 128 + kb);
      #pragma unroll
      for (int n = 0; n < 4; ++n)
        bfr[n] = *(const bf16x8*)((const char*)Bs + (wc + n * 16 + (lane & 15)) * 128 + kb);
      #pragma unroll
      for (int m = 0; m < 4; ++m)
        #pragma unroll
        for (int n = 0; n < 4; ++n)
          acc[m][n] = __builtin_amdgcn_mfma_f32_16x16x32_bf16(af[m], bfr[n], acc[m][n], 0, 0, 0);
    }
    __syncthreads();
  }

  #pragma unroll
  for (int m = 0; m < 4; ++m){
    #pragma unroll
    for (int n = 0; n < 4; ++n){
      int col = bcol + wc + n * 16 + (lane & 15);
      #pragma unroll
      for (int j = 0; j < 4; ++j){
        int row = brow + wr + m * 16 + ((lane >> 4) * 4) + j;
        float v = acc[m][n][j];
        if (EPI == 2){
          v = fmaxf(v + bias[col], 0.f);
          obf[(size_t)row * 4608 + 3840 + col] = f2bf(v);
        } else {
          v = fmaxf(v + bias[col], 0.f);
          of32[(size_t)row * 768 + col] = v;
        }
      }
    }
  }
}

// ================= split-K GEMM for hid: erepr(1024x4608) @ Wp1T -> hidp[8][1024][768] =================
// Grid 384 = 48 tiles x 8 K-slices (slice = 9 K-tiles = 576). Plain stores to
// per-slice partial buffers (deterministic, no zero-init needed); k_logits reduces.
__global__ __launch_bounds__(256) void k_gemmsk(
    const unsigned short* __restrict__ A, const unsigned short* __restrict__ Bt,
    float* __restrict__ hidp)
{
  const int K = KP1;
  __shared__ unsigned short As[128*64];
  __shared__ unsigned short Bs[128*64];
  const int t = threadIdx.x;
  const int lane = t & 63, wave = t >> 6;

  const int bid = blockIdx.x;
  const int cpx = gridDim.x >> 3;               // 48
  const int wg = (bid & 7) * cpx + (bid >> 3);  // XCD-chunked, bijective (384%8==0)
  const int ksl = wg / 48;                      // K-slice 0..7 (one per XCD chunk)
  const int tile = wg - ksl * 48;
  const int by = tile / 6, bx = tile - (tile / 6) * 6;
  const int brow = by * 128, bcol = bx * 128;

  const int wr = (wave >> 1) * 64, wc = (wave & 1) * 64;

  f32x4 acc[4][4];
  #pragma unroll
  for (int m = 0; m < 4; ++m)
    #pragma unroll
    for (int n = 0; n < 4; ++n)
      acc[m][n] = f32x4{0.f, 0.f, 0.f, 0.f};

  const int srow = wave * 8 + (lane >> 3);
  const int scol = (lane & 7) * 8;

  const unsigned short* a0 = A  + (size_t)(brow + srow) * K + scol;
  const unsigned short* b0 = Bt + (size_t)(bcol + srow) * K + scol;
  unsigned short* asdst = As + wave * 512;
  unsigned short* bsdst = Bs + wave * 512;

  const int kt0 = ksl * 9, kt1 = kt0 + 9;
  for (int kt = kt0; kt < kt1; ++kt){
    const unsigned short* ak = a0 + kt * 64;
    const unsigned short* bk = b0 + kt * 64;
    #pragma unroll
    for (int i = 0; i < 4; ++i)
      gld_lds16(ak + (size_t)i * 32 * K, asdst + i * 2048);
    #pragma unroll
    for (int i = 0; i < 4; ++i)
      gld_lds16(bk + (size_t)i * 32 * K, bsdst + i * 2048);
    __syncthreads();

    #pragma unroll
    for (int ks = 0; ks < 2; ++ks){
      bf16x8 af[4], bfr[4];
      const int kb = ks * 64 + ((lane >> 4) * 16);
      #pragma unroll
      for (int m = 0; m < 4; ++m)
        af[m] = *(const bf16x8*)((const char*)As + (wr + m * 16 + (lane & 15)) * 128 + kb);
      #pragma unroll
      for (int n = 0; n < 4; ++n)
        bfr[n] = *(const bf16x8*)((const char*)Bs + (wc + n * 16 + (lane & 15)) * 128 + kb);
      #pragma unroll
      for (int m = 0; m < 4; ++m)
        #pragma unroll
        for (int n = 0; n < 4; ++n)
          acc[m][n] = __builtin_amdgcn_mfma_f32_16x16x32_bf16(af[m], bfr[n], acc[m][n], 0, 0, 0);
    }
    __syncthreads();
  }

  float* out = hidp + (size_t)ksl * BB * HH;
  #pragma unroll
  for (int m = 0; m < 4; ++m){
    #pragma unroll
    for (int n = 0; n < 4; ++n){
      int col = bcol + wc + n * 16 + (lane & 15);
      #pragma unroll
      for (int j = 0; j < 4; ++j){
        int row = brow + wr + m * 16 + ((lane >> 4) * 4) + j;
        out[(size_t)row * 768 + col] = acc[m][n][j];
      }
    }
  }
}

// ---------------- per-graph segment sum + build bf16 [h | msg] A-buffer
// Source is bf16 hb: stage 48KB via bf16x8 copies, sum from LDS.
__global__ __launch_bounds__(256) void k_scatter(const unsigned short* __restrict__ hb,
                                                 const int* __restrict__ esrc,
                                                 const int* __restrict__ etgt,
                                                 unsigned short* __restrict__ acat){
  __shared__ unsigned short hsm[32 * 768];   // 48KB
  __shared__ int cnt[32];
  __shared__ unsigned char lst[32][64];
  const int g = blockIdx.x, t = threadIdx.x;
  const unsigned short* src = hb + (size_t)g * 32 * 768;
  #pragma unroll
  for (int i = 0; i < 12; ++i){
    const int o = (i * 256 + t) * 8;
    *(bf16x8*)(hsm + o) = *(const bf16x8*)(src + o);
  }
  if (t < 32) cnt[t] = 0;
  __syncthreads();
  if (t < 64){
    const int e = g * 64 + t;
    const int s = esrc[e] & 31, tg = etgt[e] & 31;   // intra-graph local ids
    const int slot = atomicAdd(&cnt[tg], 1);
    lst[tg][slot] = (unsigned char)s;
  }
  __syncthreads();
  for (int n = 0; n < 32; ++n){
    float s0 = 0.f, s1 = 0.f, s2 = 0.f;
    const int c = cnt[n];
    for (int e = 0; e < c; ++e){
      const unsigned short* r = hsm + (int)lst[n][e] * 768;
      s0 += bf2f(r[t]); s1 += bf2f(r[t + 256]); s2 += bf2f(r[t + 512]);
    }
    unsigned short* oa = acat + (size_t)(g * 32 + n) * 1536;
    const unsigned short* hr = hsm + n * 768;
    oa[t]       = hr[t];
    oa[t + 256] = hr[t + 256];
    oa[t + 512] = hr[t + 512];
    oa[768 + t]       = f2bf(s0);
    oa[768 + t + 256] = f2bf(s1);
    oa[768 + t + 512] = f2bf(s2);
  }
}

// ---------------- per-graph: dist + gather h_c/h_t/h_dist into edge_repr
__global__ __launch_bounds__(256) void k_build(const unsigned short* __restrict__ hb,
                                               const unsigned short* __restrict__ htext,
                                               const int* __restrict__ tni,
                                               const int* __restrict__ esrc,
                                               const int* __restrict__ etgt,
                                               const float* __restrict__ dist_emb,
                                               unsigned short* __restrict__ er){
  int g = blockIdx.x;
  int t = threadIdx.x;
  __shared__ int s_dist;
  int c = tni[g * 2 + 0], tt = tni[g * 2 + 1];
  if (t == 0){
    // reference quirk: first_edge indexed with LOCAL node ids -> graph 0's edges only
    int cu = c, tu = tt;
    for (int e = 0; e < 64; ++e){ if (esrc[e] == c){ cu = etgt[e]; break; } }
    for (int e = 0; e < 64; ++e){ if (esrc[e] == tt){ tu = etgt[e]; break; } }
    int d = cu - tu; if (d < 0) d = -d; if (d > 31) d = 31;
    s_dist = d;
  }
  __syncthreads();
  size_t rc = (size_t)(g * 32 + c) * 768, rt = (size_t)(g * 32 + tt) * 768;
  unsigned short* o = er + (size_t)g * 4608;
  int d = s_dist;
  for (int i = t; i < 768; i += 256){
    o[i]        = hb[rc + i];
    o[768 + i]  = htext[rc + i];
    o[1536 + i] = hb[rt + i];
    o[2304 + i] = htext[rt + i];
    o[3072 + i] = f2bf(dist_emb[(size_t)d * 768 + i]);
  }
}

// ---------------- logits: out[i] = relu(sum_p hidp[p][i,:] + b_p1) . W_p2 + b_p2
__global__ __launch_bounds__(256) void k_logits(const float* __restrict__ hidp,
                                                const float* __restrict__ bp1,
                                                const float* __restrict__ wp2,
                                                const float* __restrict__ bp2,
                                                float* __restrict__ out){
  int row = blockIdx.x * 4 + (threadIdx.x >> 6);
  int lane = threadIdx.x & 63;
  float s = 0.f;
  for (int j = lane; j < 768; j += 64){
    float v = 0.f;
    #pragma unroll
    for (int p = 0; p < 8; ++p)
      v += hidp[(size_t)p * BB * HH + (size_t)row * 768 + j];
    v = fmaxf(v + bp1[j], 0.f);
    s += v * wp2[j];
  }
  #pragma unroll
  for (int off = 32; off; off >>= 1) s += __shfl_down(s, off);
  if (lane == 0) out[row] = s + bp2[0];
}

extern "C" void kernel_launch(void* const* d_in, const int* in_sizes, int n_in,
                              void* d_out, int out_size, void* d_ws, size_t ws_size,
                              hipStream_t stream){
  const float* x        = (const float*)d_in[0];
  const int*   sid      = (const int*)d_in[1];
  const int*   eid      = (const int*)d_in[2];
  const int*   esrc     = (const int*)d_in[3];
  const int*   etgt     = esrc + EE;
  const int*   tni      = (const int*)d_in[4];
  const float* expl     = (const float*)d_in[5];
  const float* W_sem    = (const float*)d_in[6];
  const float* spk      = (const float*)d_in[7];
  const float* emo      = (const float*)d_in[8];
  const float* w_self   = (const float*)d_in[9];
  const float* w_nbr    = (const float*)d_in[10];
  const float* dist_emb = (const float*)d_in[11];
  const float* W_expl   = (const float*)d_in[12];
  const float* b_expl   = (const float*)d_in[13];
  const float* W_p1     = (const float*)d_in[14];
  const float* b_p1     = (const float*)d_in[15];
  const float* W_p2     = (const float*)d_in[16];
  const float* b_p2     = (const float*)d_in[17];

  char* ws = (char*)d_ws;
  size_t off = 0;
  auto alloc = [&](size_t bytes) -> void* {
    void* p = ws + off; off += (bytes + 255) & ~(size_t)255; return p;
  };
  unsigned short* hb    = (unsigned short*)alloc((size_t)NN * HH * 2);
  unsigned short* htext = (unsigned short*)alloc((size_t)NN * HH * 2);
  unsigned short* acat  = (unsigned short*)alloc((size_t)NN * KCAT * 2);
  unsigned short* WsemT = (unsigned short*)alloc((size_t)HH * KSEM * 2);
  unsigned short* WcatT = (unsigned short*)alloc((size_t)3 * HH * KCAT * 2);
  unsigned short* WexplT= (unsigned short*)alloc((size_t)HH * HH * 2);
  unsigned short* Wp1T  = (unsigned short*)alloc((size_t)HH * KP1 * 2);
  unsigned short* erepr = (unsigned short*)alloc((size_t)BB * KP1 * 2);
  float*          hidp  = (float*)alloc((size_t)8 * BB * HH * 4);
  unsigned short* explbf= (unsigned short*)alloc((size_t)BB * HH * 2);
  // xbf aliases acat: only live until sem GEMM completes; acat first written after.
  unsigned short* xbf   = acat;
  (void)ws_size; (void)in_sizes; (void)n_in; (void)out_size;

  // weight transposes (f32 -> bf16, [K][768] -> [768][K])
  k_transpose<<<dim3(KSEM/32, 24), 256, 0, stream>>>(W_sem, WsemT, KSEM, KSEM, 0);
  for (int l = 0; l < 3; ++l){
    k_transpose<<<dim3(24, 24), 256, 0, stream>>>(w_self + (size_t)l*HH*HH, WcatT + (size_t)l*HH*KCAT, HH, KCAT, 0);
    k_transpose<<<dim3(24, 24), 256, 0, stream>>>(w_nbr  + (size_t)l*HH*HH, WcatT + (size_t)l*HH*KCAT, HH, KCAT, HH);
  }
  k_transpose<<<dim3(24, 24), 256, 0, stream>>>(W_expl, WexplT, HH, HH, 0);
  k_transpose<<<dim3(KP1/32, 24), 256, 0, stream>>>(W_p1, Wp1T, KP1, KP1, 0);

  // activation casts f32 -> bf16
  k_cast<<<(NN*KSEM/8 + 255)/256, 256, 0, stream>>>(x, xbf, NN*KSEM/8);
  k_cast<<<(BB*HH/8 + 255)/256, 256, 0, stream>>>(expl, explbf, BB*HH/8);

  // h_text = relu(x @ W_sem + spk + emo)  [256x192 8-phase, 512 blocks = 2 exact rounds]
  k_gemm8<0><<<4*(NN/256), 512, 0, stream>>>(xbf, WsemT, KSEM,
      hb, htext, sid, eid, spk, emo);

  // 3 GNN layers  [256x192 8-phase]
  for (int l = 0; l < 3; ++l){
    k_scatter<<<BB, 256, 0, stream>>>(hb, esrc, etgt, acat);
    k_gemm8<1><<<4*(NN/256), 512, 0, stream>>>(acat, WcatT + (size_t)l*HH*KCAT, KCAT,
        hb, nullptr, nullptr, nullptr, nullptr, nullptr);
  }

  // z_teacher into edge_repr cols [3840,4608)  [128^2]
  k_gemm<2><<<6*(BB/128), 256, 0, stream>>>(explbf, WexplT, HH, b_expl, erepr, nullptr);

  // gather h_c/h_t/h_dist into edge_repr cols [0,3840)
  k_build<<<BB, 256, 0, stream>>>(hb, htext, tni, esrc, etgt, dist_emb, erepr);

  // hid partials = erepr @ W_p1 (split-K 8, 384 blocks)
  k_gemmsk<<<384, 256, 0, stream>>>(erepr, Wp1T, hidp);

  // logits (fused split-K reduce + bias + relu + projection)
  k_logits<<<BB/4, 256, 0, stream>>>(hidp, b_p1, W_p2, b_p2, (float*)d_out);
}

// Round 14
// 545.415 us; speedup vs baseline: 1.5247x; 1.0406x over previous
//
#include <hip/hip_runtime.h>
#include <hip/hip_bf16.h>

// Problem constants
#define NN 32768      // nodes
#define BB 1024       // graphs
#define PP 32         // nodes per graph
#define EE 65536      // edges
#define HH 768
#define KSEM 1024
#define KCAT 1536
#define KP1 4608

typedef __attribute__((ext_vector_type(8))) short bf16x8;
typedef __attribute__((ext_vector_type(4))) float f32x4;

__device__ __forceinline__ unsigned short f2bf(float f){
  union { float f; unsigned u; } v; v.f = f;
  unsigned r = v.u + 0x7FFFu + ((v.u >> 16) & 1u);
  return (unsigned short)(r >> 16);
}
__device__ __forceinline__ float bf2f(unsigned short u){
  union { unsigned u; float f; } v; v.u = ((unsigned)u) << 16; return v.f;
}

__device__ __forceinline__ void gld_lds16(const void* g, void* l){
  __builtin_amdgcn_global_load_lds(
      (const __attribute__((address_space(1))) unsigned int*)g,
      (__attribute__((address_space(3))) unsigned int*)l, 16, 0, 0);
}

// ---------------- f32 -> bf16 cast, 8 elems/thread
__global__ __launch_bounds__(256) void k_cast(const float* __restrict__ in,
                                              unsigned short* __restrict__ out, int n8){
  int i = blockIdx.x * 256 + threadIdx.x;
  if (i >= n8) return;
  const float4* p = (const float4*)(in + (size_t)i * 8);
  float4 u0 = p[0], u1 = p[1];
  unsigned short vv[8];
  vv[0]=f2bf(u0.x); vv[1]=f2bf(u0.y); vv[2]=f2bf(u0.z); vv[3]=f2bf(u0.w);
  vv[4]=f2bf(u1.x); vv[5]=f2bf(u1.y); vv[6]=f2bf(u1.z); vv[7]=f2bf(u1.w);
  *(bf16x8*)(out + (size_t)i * 8) = *(bf16x8*)vv;
}

// ---------------- weight transpose: in (Kin x 768) f32 -> out[n*ostride + ooff + k] bf16
__global__ void k_transpose(const float* __restrict__ in, unsigned short* __restrict__ out,
                            int Kin, int ostride, int ooff){
  __shared__ float tile[32][33];
  int kb = blockIdx.x * 32, nb = blockIdx.y * 32;
  int tx = threadIdx.x & 31, ty = threadIdx.x >> 5; // 32 x 8
  #pragma unroll
  for (int i = ty; i < 32; i += 8)
    tile[i][tx] = in[(size_t)(kb + i) * 768 + nb + tx];
  __syncthreads();
  #pragma unroll
  for (int i = ty; i < 32; i += 8)
    out[(size_t)(nb + i) * ostride + ooff + kb + tx] = f2bf(tile[tx][i]);
}

// ================= 256x192 8-phase GEMM (R12 loop, FROZEN) + fused segment-sum epilogue ====
// C(M x 768) = A(M x K) @ B; A bf16 row-major [M][K], Bt = [768][K] bf16.
// 512 threads = 8 waves (2M x 4N); per-wave output 128x48; BK=64; grid 512 = 2 exact rounds.
// LDS 112KB: A dbuf 2x32KB @0, B dbuf 2x24KB @65536B; st_16x32 swizzle both-sides.
// vmcnt(3) at tile boundaries (leaves next-B's 3 loads flying). Loop byte-identical to R12/R13.
// EPILOGUE (new): writes h into aN's h-half (cols 0..768 of stride-1536 [h|msg] buffer);
// if esrc != nullptr (runtime gate, NO extra instantiation), additionally computes the
// per-graph segment-sum from the bf16 h-tile stashed in (now-free) LDS and writes the
// msg-half — replacing the standalone k_scatter kernels. Tile rows = 8 whole graphs;
// msg is column-local, so the block is self-sufficient. WAITV0+BAR before LDS reuse
// (tail prefetches must land first). Ping-pong acat0/acat1 avoids read/write races.
// EPI 0: h_text = relu(acc + spk[sid]+emo[eid]); also writes htext. EPI 1: h = relu(acc)+A_hhalf.

#define BAR __builtin_amdgcn_s_barrier()
#define WAITL asm volatile("s_waitcnt lgkmcnt(0)" ::: "memory")
#define WAITV3 asm volatile("s_waitcnt vmcnt(3)" ::: "memory")
#define WAITV0 asm volatile("s_waitcnt vmcnt(0)" ::: "memory")

// stage A half-tile (128 rows x 64 cols = 16KB) = 2 gld_lds per thread
#define STG_A(buf,half,tile) { const unsigned short* s_ = aS + (size_t)((half)*128)*K + (tile)*64; \
    gld_lds16(s_,                 dA + (buf)*16384 + (half)*8192); \
    gld_lds16(s_ + (size_t)64*K,  dA + (buf)*16384 + (half)*8192 + 4096); }
// stage B third-tile (64 rows x 64 cols = 8KB) = 1 gld_lds per thread
#define STG_B1(buf,third,tile) { const unsigned short* s_ = bS + (size_t)((third)*64)*K + (tile)*64; \
    gld_lds16(s_, dB + (buf)*12288 + (third)*4096); }
// load A frags for m-quadrant q (m = 2q, 2q+1), both k-slices
#define LDA(buf,q) { _Pragma("unroll") for (int jj=0;jj<2;++jj){ \
    const int R_ = wrow*128 + ((q)*2+jj)*16 + l15; const int sw_ = ((R_>>2)&1)<<5; \
    af[jj][0] = *(const bf16x8*)((const char*)LDS + (buf)*32768 + R_*128 + ((kq)^sw_)); \
    af[jj][1] = *(const bf16x8*)((const char*)LDS + (buf)*32768 + R_*128 + ((64+kq)^sw_)); }}
// load all 3 B frags (n=0..2), both k-slices (once per K-tile, reused across 4 phases)
#define LDB(buf) { _Pragma("unroll") for (int nn=0;nn<3;++nn){ \
    const int R_ = wcol*48 + nn*16 + l15; const int sw_ = ((R_>>2)&1)<<5; \
    bfr[nn][0] = *(const bf16x8*)((const char*)LDS + 65536 + (buf)*24576 + R_*128 + ((kq)^sw_)); \
    bfr[nn][1] = *(const bf16x8*)((const char*)LDS + 65536 + (buf)*24576 + R_*128 + ((64+kq)^sw_)); }}
#define MMA(q) { __builtin_amdgcn_s_setprio(1); \
    _Pragma("unroll") for (int jj=0;jj<2;++jj) _Pragma("unroll") for (int nn=0;nn<3;++nn){ \
      acc[(q)*2+jj][nn] = __builtin_amdgcn_mfma_f32_16x16x32_bf16(af[jj][0], bfr[nn][0], acc[(q)*2+jj][nn],0,0,0); \
      acc[(q)*2+jj][nn] = __builtin_amdgcn_mfma_f32_16x16x32_bf16(af[jj][1], bfr[nn][1], acc[(q)*2+jj][nn],0,0,0); } \
    __builtin_amdgcn_s_setprio(0); }

template<int EPI>
__global__ __launch_bounds__(512, 2) void k_gemm8(
    const unsigned short* __restrict__ A, const unsigned short* __restrict__ Bt, int K,
    unsigned short* __restrict__ aN, unsigned short* __restrict__ htext,
    const int* __restrict__ sid, const int* __restrict__ eid,
    const float* __restrict__ spk, const float* __restrict__ emo,
    const int* __restrict__ esrc, const int* __restrict__ etgt)
{
  __shared__ unsigned short LDS[57344];   // 112 KiB: A [0,32768) shorts, B [32768,57344)
  const int t = threadIdx.x;
  const int lane = t & 63, w = t >> 6;
  const int wrow = w >> 2, wcol = w & 3;

  // bijective XCD-chunked swizzle (gridDim.x % 8 == 0), col-fastest (4 col panels)
  const int bid = blockIdx.x;
  const int cpx = gridDim.x >> 3;
  const int wg = (bid & 7) * cpx + (bid >> 3);
  const int by = wg >> 2, bx = wg & 3;
  const int brow = by * 256, bcol = bx * 192;

  f32x4 acc[8][3];
  #pragma unroll
  for (int m = 0; m < 8; ++m)
    #pragma unroll
    for (int n = 0; n < 3; ++n) acc[m][n] = f32x4{0.f,0.f,0.f,0.f};

  // staging: thread t covers row (t>>3) of a 64-row issue, cols 8*(t&7)..+8,
  // with source column pre-swizzled so linear LDS ends up st_16x32-swizzled.
  const int srow = t >> 3;
  const int scol = ((t & 7) * 8) ^ (((t >> 5) & 1) << 4);
  const unsigned short* aS = A  + (size_t)(brow + srow) * K + scol;
  const unsigned short* bS = Bt + (size_t)(bcol + srow) * K + scol;
  unsigned short* dA = LDS + (size_t)w * 512;
  unsigned short* dB = LDS + 32768 + (size_t)w * 512;
  const int l15 = lane & 15, kq = (lane >> 4) * 16;  // kq in bytes
  const int nkt = K >> 6, niter = nkt >> 1;

  bf16x8 af[2][2], bfr[3][2];

  // prologue: B(0) x3, A(0) x4, B(1) x3; wait tile0's 7, leave B(1)'s 3 flying
  STG_B1(0,0,0); STG_B1(0,1,0); STG_B1(0,2,0);
  STG_A(0,0,0);  STG_A(0,1,0);
  STG_B1(1,0,1); STG_B1(1,1,1); STG_B1(1,2,1);
  WAITV3;
  BAR;

  for (int i = 0; i < niter; ++i){
    const int t1 = 2*i+1;
    const int t2 = (2*i+2 < nkt) ? 2*i+2 : nkt-1;   // tail: re-fetch valid tile, data unused
    const int t3 = (2*i+3 < nkt) ? 2*i+3 : nkt-1;
    // ---- tile 2i from buf0 ----
    LDA(0,0); LDB(0); STG_A(1,0,t1);                 // buf1.A freed at prev ph8
    BAR; WAITL; MMA(0); BAR;                         // ph1
    LDA(0,1);         STG_A(1,1,t1);
    BAR; WAITL; MMA(1); BAR;                         // ph2
    LDA(0,2);         STG_B1(0,0,t2); STG_B1(0,1,t2); // buf0.B freed at ph1
    BAR; WAITL; MMA(2); BAR;                         // ph3
    LDA(0,3);         STG_B1(0,2,t2);
    BAR; WAITL; MMA(3);
    WAITV3; BAR;                                     // ph4: A(t1)+B(t1) landed (leaves B(t2) x3)
    // ---- tile 2i+1 from buf1 ----
    LDA(1,0); LDB(1); STG_A(0,0,t2);                 // buf0.A freed at ph4
    BAR; WAITL; MMA(0); BAR;                         // ph5
    LDA(1,1);         STG_A(0,1,t2);
    BAR; WAITL; MMA(1); BAR;                         // ph6
    LDA(1,2);         STG_B1(1,0,t3); STG_B1(1,1,t3); // buf1.B freed at ph5
    BAR; WAITL; MMA(2); BAR;                         // ph7
    LDA(1,3);         STG_B1(1,2,t3);
    BAR; WAITL; MMA(3);
    WAITV3; BAR;                                     // ph8: A(t2)+B(t2) landed (leaves B(t3) x3)
  }
  WAITV0;  // drain this wave's tail prefetches
  BAR;     // ALL waves drained -> LDS safe to repurpose

  // ---- epilogue step 1: h writes (global) + bf16 stash to LDS ----
  // C/D layout col=lane&15, row=(lane>>4)*4+reg
  unsigned short* hs = LDS;   // [256][192] bf16 = 96KB
  #pragma unroll
  for (int m = 0; m < 8; ++m){
    #pragma unroll
    for (int n = 0; n < 3; ++n){
      const int col_l = wcol*48 + n*16 + l15;
      const int col = bcol + col_l;
      #pragma unroll
      for (int j = 0; j < 4; ++j){
        const int row_l = wrow*128 + m*16 + ((lane>>4)*4) + j;
        const int row = brow + row_l;
        float v = acc[m][n][j];
        unsigned short b;
        if (EPI == 0){
          float e = spk[sid[row] * 768 + col] + emo[eid[row] * 768 + col];
          v = fmaxf(v + e, 0.f);
          b = f2bf(v);
          htext[(size_t)row * 768 + col] = b;
        } else {
          v = fmaxf(v, 0.f) + bf2f(A[(size_t)row * K + col]);  // residual = acatPrev h-half
          b = f2bf(v);
        }
        aN[(size_t)row * 1536 + col] = b;   // h-half of [h|msg]
        hs[row_l * 192 + col_l] = b;
      }
    }
  }

  // ---- epilogue step 2 (runtime-gated): per-graph segment-sum -> msg-half ----
  if (esrc != nullptr){
    int* cnt            = (int*)((char*)LDS + 98304);            // [256]
    unsigned short* off = (unsigned short*)((char*)LDS + 99328); // [8][33]
    unsigned char* srt  = (unsigned char*)((char*)LDS + 99904);  // [8][64]
    int* wcur           = (int*)((char*)LDS + 100416);           // [256]
    if (t < 256) cnt[t] = 0;
    __syncthreads();
    const int g = t >> 6;
    const int ge = (by*8 + g)*64 + (t & 63);
    const int es = esrc[ge] & 31, et = etgt[ge] & 31;   // intra-graph local ids
    atomicAdd(&cnt[g*32 + et], 1);
    __syncthreads();
    if (t < 8){
      int o = 0;
      for (int n2 = 0; n2 < 32; ++n2){
        off[t*33 + n2] = (unsigned short)o;
        wcur[t*32 + n2] = o;
        o += cnt[t*32 + n2];
      }
      off[t*33 + 32] = (unsigned short)o;
    }
    __syncthreads();
    {
      const int slot = atomicAdd(&wcur[g*32 + et], 1);
      srt[g*64 + slot] = (unsigned char)es;
    }
    __syncthreads();
    // wave w handles (graph,node) pairs w, w+8, ...; lane covers 3 cols {lane, +64, +128}
    for (int pp = w; pp < 256; pp += 8){
      const int gg = pp >> 5, n2 = pp & 31;
      const int o0 = off[gg*33 + n2], o1 = off[gg*33 + n2 + 1];
      float s0 = 0.f, s1 = 0.f, s2 = 0.f;
      for (int k2 = o0; k2 < o1; ++k2){
        const unsigned short* r = hs + (gg*32 + (int)srt[gg*64 + k2]) * 192;
        s0 += bf2f(r[lane]); s1 += bf2f(r[lane + 64]); s2 += bf2f(r[lane + 128]);
      }
      unsigned short* o = aN + (size_t)(brow + pp) * 1536 + 768 + bcol;
      o[lane]       = f2bf(s0);
      o[lane + 64]  = f2bf(s1);
      o[lane + 128] = f2bf(s2);
    }
  }
}

// ================= 128x128 m97-style GEMM (z_teacher only) =================
// EPI 2: z = relu(acc + bias) -> obf at col base 3840, stride 4608 (edge_repr)
template<int EPI>
__global__ __launch_bounds__(256) void k_gemm(
    const unsigned short* __restrict__ A, const unsigned short* __restrict__ Bt, int K,
    const float* __restrict__ bias,
    unsigned short* __restrict__ obf, float* __restrict__ of32)
{
  __shared__ unsigned short As[128*64];
  __shared__ unsigned short Bs[128*64];
  const int t = threadIdx.x;
  const int lane = t & 63, wave = t >> 6;

  const int bid = blockIdx.x;
  const int cpx = gridDim.x >> 3;
  const int wg = (bid & 7) * cpx + (bid >> 3);
  const int by = wg / 6;
  const int bx = wg - by * 6;
  const int brow = by * 128;
  const int bcol = bx * 128;

  const int wr = (wave >> 1) * 64, wc = (wave & 1) * 64;

  f32x4 acc[4][4];
  #pragma unroll
  for (int m = 0; m < 4; ++m)
    #pragma unroll
    for (int n = 0; n < 4; ++n)
      acc[m][n] = f32x4{0.f, 0.f, 0.f, 0.f};

  const int srow = wave * 8 + (lane >> 3);
  const int scol = (lane & 7) * 8;
  const int nkt = K >> 6;

  const unsigned short* a0 = A  + (size_t)(brow + srow) * K + scol;
  const unsigned short* b0 = Bt + (size_t)(bcol + srow) * K + scol;
  unsigned short* asdst = As + wave * 512;
  unsigned short* bsdst = Bs + wave * 512;

  for (int kt = 0; kt < nkt; ++kt){
    const unsigned short* ak = a0 + kt * 64;
    const unsigned short* bk = b0 + kt * 64;
    #pragma unroll
    for (int i = 0; i < 4; ++i)
      gld_lds16(ak + (size_t)i * 32 * K, asdst + i * 2048);
    #pragma unroll
    for (int i = 0; i < 4; ++i)
      gld_lds16(bk + (size_t)i * 32 * K, bsdst + i * 2048);
    __syncthreads();

    #pragma unroll
    for (int ks = 0; ks < 2; ++ks){
      bf16x8 af[4], bfr[4];
      const int kb = ks * 64 + ((lane >> 4) * 16);
      #pragma unroll
      for (int m = 0; m < 4; ++m)
        af[m] = *(const bf16x8*)((const char*)As + (wr + m * 16 + (lane & 15)) * 128 + kb);
      #pragma unroll
      for (int n = 0; n < 4; ++n)
        bfr[n] = *(const bf16x8*)((const char*)Bs + (wc + n * 16 + (lane & 15)) * 128 + kb);
      #pragma unroll
      for (int m = 0; m < 4; ++m)
        #pragma unroll
        for (int n = 0; n < 4; ++n)
          acc[m][n] = __builtin_amdgcn_mfma_f32_16x16x32_bf16(af[m], bfr[n], acc[m][n], 0, 0, 0);
    }
    __syncthreads();
  }

  #pragma unroll
  for (int m = 0; m < 4; ++m){
    #pragma unroll
    for (int n = 0; n < 4; ++n){
      int col = bcol + wc + n * 16 + (lane & 15);
      #pragma unroll
      for (int j = 0; j < 4; ++j){
        int row = brow + wr + m * 16 + ((lane >> 4) * 4) + j;
        float v = acc[m][n][j];
        if (EPI == 2){
          v = fmaxf(v + bias[col], 0.f);
          obf[(size_t)row * 4608 + 3840 + col] = f2bf(v);
        } else {
          v = fmaxf(v + bias[col], 0.f);
          of32[(size_t)row * 768 + col] = v;
        }
      }
    }
  }
}

// ================= split-K GEMM for hid: erepr(1024x4608) @ Wp1T -> hidp[8][1024][768] =================
// Grid 384 = 48 tiles x 8 K-slices (slice = 9 K-tiles = 576). Plain stores to
// per-slice partial buffers (deterministic, no zero-init needed); k_logits reduces.
__global__ __launch_bounds__(256) void k_gemmsk(
    const unsigned short* __restrict__ A, const unsigned short* __restrict__ Bt,
    float* __restrict__ hidp)
{
  const int K = KP1;
  __shared__ unsigned short As[128*64];
  __shared__ unsigned short Bs[128*64];
  const int t = threadIdx.x;
  const int lane = t & 63, wave = t >> 6;

  const int bid = blockIdx.x;
  const int cpx = gridDim.x >> 3;               // 48
  const int wg = (bid & 7) * cpx + (bid >> 3);  // XCD-chunked, bijective (384%8==0)
  const int ksl = wg / 48;                      // K-slice 0..7
  const int tile = wg - ksl * 48;
  const int by = tile / 6, bx = tile - (tile / 6) * 6;
  const int brow = by * 128, bcol = bx * 128;

  const int wr = (wave >> 1) * 64, wc = (wave & 1) * 64;

  f32x4 acc[4][4];
  #pragma unroll
  for (int m = 0; m < 4; ++m)
    #pragma unroll
    for (int n = 0; n < 4; ++n)
      acc[m][n] = f32x4{0.f, 0.f, 0.f, 0.f};

  const int srow = wave * 8 + (lane >> 3);
  const int scol = (lane & 7) * 8;

  const unsigned short* a0 = A  + (size_t)(brow + srow) * K + scol;
  const unsigned short* b0 = Bt + (size_t)(bcol + srow) * K + scol;
  unsigned short* asdst = As + wave * 512;
  unsigned short* bsdst = Bs + wave * 512;

  const int kt0 = ksl * 9, kt1 = kt0 + 9;
  for (int kt = kt0; kt < kt1; ++kt){
    const unsigned short* ak = a0 + kt * 64;
    const unsigned short* bk = b0 + kt * 64;
    #pragma unroll
    for (int i = 0; i < 4; ++i)
      gld_lds16(ak + (size_t)i * 32 * K, asdst + i * 2048);
    #pragma unroll
    for (int i = 0; i < 4; ++i)
      gld_lds16(bk + (size_t)i * 32 * K, bsdst + i * 2048);
    __syncthreads();

    #pragma unroll
    for (int ks = 0; ks < 2; ++ks){
      bf16x8 af[4], bfr[4];
      const int kb = ks * 64 + ((lane >> 4) * 16);
      #pragma unroll
      for (int m = 0; m < 4; ++m)
        af[m] = *(const bf16x8*)((const char*)As + (wr + m * 16 + (lane & 15)) * 128 + kb);
      #pragma unroll
      for (int n = 0; n < 4; ++n)
        bfr[n] = *(const bf16x8*)((const char*)Bs + (wc + n * 16 + (lane & 15)) * 128 + kb);
      #pragma unroll
      for (int m = 0; m < 4; ++m)
        #pragma unroll
        for (int n = 0; n < 4; ++n)
          acc[m][n] = __builtin_amdgcn_mfma_f32_16x16x32_bf16(af[m], bfr[n], acc[m][n], 0, 0, 0);
    }
    __syncthreads();
  }

  float* out = hidp + (size_t)ksl * BB * HH;
  #pragma unroll
  for (int m = 0; m < 4; ++m){
    #pragma unroll
    for (int n = 0; n < 4; ++n){
      int col = bcol + wc + n * 16 + (lane & 15);
      #pragma unroll
      for (int j = 0; j < 4; ++j){
        int row = brow + wr + m * 16 + ((lane >> 4) * 4) + j;
        out[(size_t)row * 768 + col] = acc[m][n][j];
      }
    }
  }
}

// ---------------- per-graph: dist + gather h_c/h_t/h_dist into edge_repr
// h now lives in acat's h-half (stride 1536).
__global__ __launch_bounds__(256) void k_build(const unsigned short* __restrict__ acatH,
                                               const unsigned short* __restrict__ htext,
                                               const int* __restrict__ tni,
                                               const int* __restrict__ esrc,
                                               const int* __restrict__ etgt,
                                               const float* __restrict__ dist_emb,
                                               unsigned short* __restrict__ er){
  int g = blockIdx.x;
  int t = threadIdx.x;
  __shared__ int s_dist;
  int c = tni[g * 2 + 0], tt = tni[g * 2 + 1];
  if (t == 0){
    // reference quirk: first_edge indexed with LOCAL node ids -> graph 0's edges only
    int cu = c, tu = tt;
    for (int e = 0; e < 64; ++e){ if (esrc[e] == c){ cu = etgt[e]; break; } }
    for (int e = 0; e < 64; ++e){ if (esrc[e] == tt){ tu = etgt[e]; break; } }
    int d = cu - tu; if (d < 0) d = -d; if (d > 31) d = 31;
    s_dist = d;
  }
  __syncthreads();
  size_t rc = (size_t)(g * 32 + c) * 1536, rt = (size_t)(g * 32 + tt) * 1536;
  size_t rc8 = (size_t)(g * 32 + c) * 768, rt8 = (size_t)(g * 32 + tt) * 768;
  unsigned short* o = er + (size_t)g * 4608;
  int d = s_dist;
  for (int i = t; i < 768; i += 256){
    o[i]        = acatH[rc + i];
    o[768 + i]  = htext[rc8 + i];
    o[1536 + i] = acatH[rt + i];
    o[2304 + i] = htext[rt8 + i];
    o[3072 + i] = f2bf(dist_emb[(size_t)d * 768 + i]);
  }
}

// ---------------- logits: out[i] = relu(sum_p hidp[p][i,:] + b_p1) . W_p2 + b_p2
__global__ __launch_bounds__(256) void k_logits(const float* __restrict__ hidp,
                                                const float* __restrict__ bp1,
                                                const float* __restrict__ wp2,
                                                const float* __restrict__ bp2,
                                                float* __restrict__ out){
  int row = blockIdx.x * 4 + (threadIdx.x >> 6);
  int lane = threadIdx.x & 63;
  float s = 0.f;
  for (int j = lane; j < 768; j += 64){
    float v = 0.f;
    #pragma unroll
    for (int p = 0; p < 8; ++p)
      v += hidp[(size_t)p * BB * HH + (size_t)row * 768 + j];
    v = fmaxf(v + bp1[j], 0.f);
    s += v * wp2[j];
  }
  #pragma unroll
  for (int off = 32; off; off >>= 1) s += __shfl_down(s, off);
  if (lane == 0) out[row] = s + bp2[0];
}

extern "C" void kernel_launch(void* const* d_in, const int* in_sizes, int n_in,
                              void* d_out, int out_size, void* d_ws, size_t ws_size,
                              hipStream_t stream){
  const float* x        = (const float*)d_in[0];
  const int*   sid      = (const int*)d_in[1];
  const int*   eid      = (const int*)d_in[2];
  const int*   esrc     = (const int*)d_in[3];
  const int*   etgt     = esrc + EE;
  const int*   tni      = (const int*)d_in[4];
  const float* expl     = (const float*)d_in[5];
  const float* W_sem    = (const float*)d_in[6];
  const float* spk      = (const float*)d_in[7];
  const float* emo      = (const float*)d_in[8];
  const float* w_self   = (const float*)d_in[9];
  const float* w_nbr    = (const float*)d_in[10];
  const float* dist_emb = (const float*)d_in[11];
  const float* W_expl   = (const float*)d_in[12];
  const float* b_expl   = (const float*)d_in[13];
  const float* W_p1     = (const float*)d_in[14];
  const float* b_p1     = (const float*)d_in[15];
  const float* W_p2     = (const float*)d_in[16];
  const float* b_p2     = (const float*)d_in[17];

  char* ws = (char*)d_ws;
  size_t off = 0;
  auto alloc = [&](size_t bytes) -> void* {
    void* p = ws + off; off += (bytes + 255) & ~(size_t)255; return p;
  };
  unsigned short* acat0 = (unsigned short*)alloc((size_t)NN * KCAT * 2);
  unsigned short* acat1 = (unsigned short*)alloc((size_t)NN * KCAT * 2);
  unsigned short* xbf   = (unsigned short*)alloc((size_t)NN * KSEM * 2);
  unsigned short* htext = (unsigned short*)alloc((size_t)NN * HH * 2);
  unsigned short* WsemT = (unsigned short*)alloc((size_t)HH * KSEM * 2);
  unsigned short* WcatT = (unsigned short*)alloc((size_t)3 * HH * KCAT * 2);
  unsigned short* WexplT= (unsigned short*)alloc((size_t)HH * HH * 2);
  unsigned short* Wp1T  = (unsigned short*)alloc((size_t)HH * KP1 * 2);
  unsigned short* erepr = (unsigned short*)alloc((size_t)BB * KP1 * 2);
  float*          hidp  = (float*)alloc((size_t)8 * BB * HH * 4);
  unsigned short* explbf= (unsigned short*)alloc((size_t)BB * HH * 2);
  (void)ws_size; (void)in_sizes; (void)n_in; (void)out_size;

  // weight transposes (f32 -> bf16, [K][768] -> [768][K])
  k_transpose<<<dim3(KSEM/32, 24), 256, 0, stream>>>(W_sem, WsemT, KSEM, KSEM, 0);
  for (int l = 0; l < 3; ++l){
    k_transpose<<<dim3(24, 24), 256, 0, stream>>>(w_self + (size_t)l*HH*HH, WcatT + (size_t)l*HH*KCAT, HH, KCAT, 0);
    k_transpose<<<dim3(24, 24), 256, 0, stream>>>(w_nbr  + (size_t)l*HH*HH, WcatT + (size_t)l*HH*KCAT, HH, KCAT, HH);
  }
  k_transpose<<<dim3(24, 24), 256, 0, stream>>>(W_expl, WexplT, HH, HH, 0);
  k_transpose<<<dim3(KP1/32, 24), 256, 0, stream>>>(W_p1, Wp1T, KP1, KP1, 0);

  // activation casts f32 -> bf16
  k_cast<<<(NN*KSEM/8 + 255)/256, 256, 0, stream>>>(x, xbf, NN*KSEM/8);
  k_cast<<<(BB*HH/8 + 255)/256, 256, 0, stream>>>(expl, explbf, BB*HH/8);

  // h_text = relu(x @ W_sem + spk + emo) -> acat0 [h|msg] + htext
  k_gemm8<0><<<4*(NN/256), 512, 0, stream>>>(xbf, WsemT, KSEM,
      acat0, htext, sid, eid, spk, emo, esrc, etgt);

  // GNN layers, msg fused into epilogue; ping-pong acat buffers
  k_gemm8<1><<<4*(NN/256), 512, 0, stream>>>(acat0, WcatT + (size_t)0*HH*KCAT, KCAT,
      acat1, nullptr, nullptr, nullptr, nullptr, nullptr, esrc, etgt);
  k_gemm8<1><<<4*(NN/256), 512, 0, stream>>>(acat1, WcatT + (size_t)1*HH*KCAT, KCAT,
      acat0, nullptr, nullptr, nullptr, nullptr, nullptr, esrc, etgt);
  k_gemm8<1><<<4*(NN/256), 512, 0, stream>>>(acat0, WcatT + (size_t)2*HH*KCAT, KCAT,
      acat1, nullptr, nullptr, nullptr, nullptr, nullptr, nullptr, nullptr);  // msg skipped

  // z_teacher into edge_repr cols [3840,4608)  [128^2]
  k_gemm<2><<<6*(BB/128), 256, 0, stream>>>(explbf, WexplT, HH, b_expl, erepr, nullptr);

  // gather h_c/h_t/h_dist into edge_repr cols [0,3840); final h = acat1 h-half
  k_build<<<BB, 256, 0, stream>>>(acat1, htext, tni, esrc, etgt, dist_emb, erepr);

  // hid partials = erepr @ W_p1 (split-K 8, 384 blocks)
  k_gemmsk<<<384, 256, 0, stream>>>(erepr, Wp1T, hidp);

  // logits (fused split-K reduce + bias + relu + projection)
  k_logits<<<BB/4, 256, 0, stream>>>(hidp, b_p1, W_p2, b_p2, (float*)d_out);
}

// Round 15
// 529.123 us; speedup vs baseline: 1.5716x; 1.0308x over previous
//
#include <hip/hip_runtime.h>
#include <hip/hip_bf16.h>

// Problem constants
#define NN 32768      // nodes
#define BB 1024       // graphs
#define PP 32         // nodes per graph
#define EE 65536      // edges
#define HH 768
#define KSEM 1024
#define KCAT 1536
#define KP1 4608

typedef __attribute__((ext_vector_type(8))) short bf16x8;
typedef __attribute__((ext_vector_type(4))) float f32x4;

__device__ __forceinline__ unsigned short f2bf(float f){
  union { float f; unsigned u; } v; v.f = f;
  unsigned r = v.u + 0x7FFFu + ((v.u >> 16) & 1u);
  return (unsigned short)(r >> 16);
}
__device__ __forceinline__ float bf2f(unsigned short u){
  union { unsigned u; float f; } v; v.u = ((unsigned)u) << 16; return v.f;
}

__device__ __forceinline__ void gld_lds16(const void* g, void* l){
  __builtin_amdgcn_global_load_lds(
      (const __attribute__((address_space(1))) unsigned int*)g,
      (__attribute__((address_space(3))) unsigned int*)l, 16, 0, 0);
}

// ---------------- f32 -> bf16 cast, 8 elems/thread
__global__ __launch_bounds__(256) void k_cast(const float* __restrict__ in,
                                              unsigned short* __restrict__ out, int n8){
  int i = blockIdx.x * 256 + threadIdx.x;
  if (i >= n8) return;
  const float4* p = (const float4*)(in + (size_t)i * 8);
  float4 u0 = p[0], u1 = p[1];
  unsigned short vv[8];
  vv[0]=f2bf(u0.x); vv[1]=f2bf(u0.y); vv[2]=f2bf(u0.z); vv[3]=f2bf(u0.w);
  vv[4]=f2bf(u1.x); vv[5]=f2bf(u1.y); vv[6]=f2bf(u1.z); vv[7]=f2bf(u1.w);
  *(bf16x8*)(out + (size_t)i * 8) = *(bf16x8*)vv;
}

// ---------------- weight transpose: in (Kin x 768) f32 -> out[n*ostride + ooff + k] bf16
__global__ void k_transpose(const float* __restrict__ in, unsigned short* __restrict__ out,
                            int Kin, int ostride, int ooff){
  __shared__ float tile[32][33];
  int kb = blockIdx.x * 32, nb = blockIdx.y * 32;
  int tx = threadIdx.x & 31, ty = threadIdx.x >> 5; // 32 x 8
  #pragma unroll
  for (int i = ty; i < 32; i += 8)
    tile[i][tx] = in[(size_t)(kb + i) * 768 + nb + tx];
  __syncthreads();
  #pragma unroll
  for (int i = ty; i < 32; i += 8)
    out[(size_t)(nb + i) * ostride + ooff + kb + tx] = f2bf(tile[tx][i]);
}

// ================= 128x192 8-phase GEMM, 256 threads = 4 waves -> 2 blocks/CU co-resident ====
// Same per-wave program as R12/R14 (acc[8][3]; 16 A + 6 B ds_read_b128, 48 MFMA per K-tile);
// block halved so TWO blocks fit per CU (regs 96V+96A=192<=256 -> 2 waves/SIMD; LDS 80KB x2 = 160).
// Cross-block overlap (m114) hides each block's stage/drain stalls -- the lever R11 missed
// (512-thread blocks already fill the CU wave budget, so LDS shrink alone gained nothing).
// Grid = (M/128) x 4 = 1024 blocks = 2 exact rounds of 512 co-resident.
// LDS 80KB: A dbuf 2x16KB @0, B dbuf 2x24KB @32768B; st_16x32 swizzle both-sides (unchanged).
// vmcnt(6) at tile boundaries: in-flight = next-A(4) + nextnext-B(6); leaves B's 6 flying.
// EPILOGUE (R14 semantics): h -> aN h-half (stride 1536); if esrc!=nullptr, fused per-graph
// segment-sum from bf16 h-tile stashed in LDS (tile = 4 whole graphs) -> msg-half.
// EPI 0: h_text = relu(acc + spk+emo), also htext. EPI 1: h = relu(acc) + A_hhalf.

#define BAR __builtin_amdgcn_s_barrier()
#define WAITL asm volatile("s_waitcnt lgkmcnt(0)" ::: "memory")
#define WAITV6 asm volatile("s_waitcnt vmcnt(6)" ::: "memory")
#define WAITV0 asm volatile("s_waitcnt vmcnt(0)" ::: "memory")

// stage A half-tile (64 rows x 64 cols = 8KB) = 2 gld_lds per thread (issue = 32 rows)
#define STG_A(buf,half,tile) { const unsigned short* s_ = aS + (size_t)((half)*64)*K + (tile)*64; \
    gld_lds16(s_,                 dA + (buf)*8192 + (half)*4096); \
    gld_lds16(s_ + (size_t)32*K,  dA + (buf)*8192 + (half)*4096 + 2048); }
// stage B third-tile (64 rows x 64 cols = 8KB) = 2 gld_lds per thread
#define STG_B1(buf,third,tile) { const unsigned short* s_ = bS + (size_t)((third)*64)*K + (tile)*64; \
    gld_lds16(s_,                 dB + (buf)*12288 + (third)*4096); \
    gld_lds16(s_ + (size_t)32*K,  dB + (buf)*12288 + (third)*4096 + 2048); }
// load A frags for m-quadrant q (m = 2q, 2q+1), both k-slices (wrow == 0: tile has 128 rows)
#define LDA(buf,q) { _Pragma("unroll") for (int jj=0;jj<2;++jj){ \
    const int R_ = ((q)*2+jj)*16 + l15; const int sw_ = ((R_>>2)&1)<<5; \
    af[jj][0] = *(const bf16x8*)((const char*)LDS + (buf)*16384 + R_*128 + ((kq)^sw_)); \
    af[jj][1] = *(const bf16x8*)((const char*)LDS + (buf)*16384 + R_*128 + ((64+kq)^sw_)); }}
// load all 3 B frags (n=0..2), both k-slices (once per K-tile, reused across 4 phases)
#define LDB(buf) { _Pragma("unroll") for (int nn=0;nn<3;++nn){ \
    const int R_ = wcol*48 + nn*16 + l15; const int sw_ = ((R_>>2)&1)<<5; \
    bfr[nn][0] = *(const bf16x8*)((const char*)LDS + 32768 + (buf)*24576 + R_*128 + ((kq)^sw_)); \
    bfr[nn][1] = *(const bf16x8*)((const char*)LDS + 32768 + (buf)*24576 + R_*128 + ((64+kq)^sw_)); }}
#define MMA(q) { __builtin_amdgcn_s_setprio(1); \
    _Pragma("unroll") for (int jj=0;jj<2;++jj) _Pragma("unroll") for (int nn=0;nn<3;++nn){ \
      acc[(q)*2+jj][nn] = __builtin_amdgcn_mfma_f32_16x16x32_bf16(af[jj][0], bfr[nn][0], acc[(q)*2+jj][nn],0,0,0); \
      acc[(q)*2+jj][nn] = __builtin_amdgcn_mfma_f32_16x16x32_bf16(af[jj][1], bfr[nn][1], acc[(q)*2+jj][nn],0,0,0); } \
    __builtin_amdgcn_s_setprio(0); }

template<int EPI>
__global__ __launch_bounds__(256, 2) void k_gemm8(
    const unsigned short* __restrict__ A, const unsigned short* __restrict__ Bt, int K,
    unsigned short* __restrict__ aN, unsigned short* __restrict__ htext,
    const int* __restrict__ sid, const int* __restrict__ eid,
    const float* __restrict__ spk, const float* __restrict__ emo,
    const int* __restrict__ esrc, const int* __restrict__ etgt)
{
  __shared__ unsigned short LDS[40960];   // 80 KiB: A [0,16384) shorts, B [16384,40960)
  const int t = threadIdx.x;
  const int lane = t & 63, w = t >> 6;    // 4 waves, 1M x 4N
  const int wcol = w;

  // bijective XCD-chunked swizzle (gridDim.x % 8 == 0), col-fastest (4 col panels)
  const int bid = blockIdx.x;
  const int cpx = gridDim.x >> 3;
  const int wg = (bid & 7) * cpx + (bid >> 3);
  const int by = wg >> 2, bx = wg & 3;
  const int brow = by * 128, bcol = bx * 192;

  f32x4 acc[8][3];
  #pragma unroll
  for (int m = 0; m < 8; ++m)
    #pragma unroll
    for (int n = 0; n < 3; ++n) acc[m][n] = f32x4{0.f,0.f,0.f,0.f};

  // staging: thread t covers row (t>>3) of a 32-row issue, cols 8*(t&7)..+8,
  // source column pre-swizzled (key = row&4 bit) so linear LDS ends up st_16x32-swizzled.
  const int srow = t >> 3;
  const int scol = ((t & 7) * 8) ^ (((t >> 5) & 1) << 4);
  const unsigned short* aS = A  + (size_t)(brow + srow) * K + scol;
  const unsigned short* bS = Bt + (size_t)(bcol + srow) * K + scol;
  unsigned short* dA = LDS + (size_t)w * 512;            // wave writes 8 rows = 1KB per issue
  unsigned short* dB = LDS + 16384 + (size_t)w * 512;
  const int l15 = lane & 15, kq = (lane >> 4) * 16;      // kq in bytes
  const int nkt = K >> 6, niter = nkt >> 1;

  bf16x8 af[2][2], bfr[3][2];

  // prologue: B(0) x6, A(0) x4, B(1) x6; wait tile0's 10, leave B(1)'s 6 flying
  STG_B1(0,0,0); STG_B1(0,1,0); STG_B1(0,2,0);
  STG_A(0,0,0);  STG_A(0,1,0);
  STG_B1(1,0,1); STG_B1(1,1,1); STG_B1(1,2,1);
  WAITV6;
  BAR;

  for (int i = 0; i < niter; ++i){
    const int t1 = 2*i+1;
    const int t2 = (2*i+2 < nkt) ? 2*i+2 : nkt-1;   // tail: re-fetch valid tile, data unused
    const int t3 = (2*i+3 < nkt) ? 2*i+3 : nkt-1;
    // ---- tile 2i from buf0 ----
    LDA(0,0); LDB(0); STG_A(1,0,t1);                 // buf1.A freed at prev ph8
    BAR; WAITL; MMA(0); BAR;                         // ph1
    LDA(0,1);         STG_A(1,1,t1);
    BAR; WAITL; MMA(1); BAR;                         // ph2
    LDA(0,2);         STG_B1(0,0,t2); STG_B1(0,1,t2); // buf0.B freed at ph1
    BAR; WAITL; MMA(2); BAR;                         // ph3
    LDA(0,3);         STG_B1(0,2,t2);
    BAR; WAITL; MMA(3);
    WAITV6; BAR;                                     // ph4: A(t1)+B(t1) landed (leaves B(t2) x6)
    // ---- tile 2i+1 from buf1 ----
    LDA(1,0); LDB(1); STG_A(0,0,t2);                 // buf0.A freed at ph4
    BAR; WAITL; MMA(0); BAR;                         // ph5
    LDA(1,1);         STG_A(0,1,t2);
    BAR; WAITL; MMA(1); BAR;                         // ph6
    LDA(1,2);         STG_B1(1,0,t3); STG_B1(1,1,t3); // buf1.B freed at ph5
    BAR; WAITL; MMA(2); BAR;                         // ph7
    LDA(1,3);         STG_B1(1,2,t3);
    BAR; WAITL; MMA(3);
    WAITV6; BAR;                                     // ph8: A(t2)+B(t2) landed (leaves B(t3) x6)
  }
  WAITV0;  // drain this wave's tail prefetches
  BAR;     // ALL waves drained -> LDS safe to repurpose

  // ---- epilogue step 1: h writes (global) + bf16 stash to LDS ----
  // C/D layout col=lane&15, row=(lane>>4)*4+reg
  unsigned short* hs = LDS;   // [128][192] bf16 = 48KB
  #pragma unroll
  for (int m = 0; m < 8; ++m){
    #pragma unroll
    for (int n = 0; n < 3; ++n){
      const int col_l = wcol*48 + n*16 + l15;
      const int col = bcol + col_l;
      #pragma unroll
      for (int j = 0; j < 4; ++j){
        const int row_l = m*16 + ((lane>>4)*4) + j;
        const int row = brow + row_l;
        float v = acc[m][n][j];
        unsigned short b;
        if (EPI == 0){
          float e = spk[sid[row] * 768 + col] + emo[eid[row] * 768 + col];
          v = fmaxf(v + e, 0.f);
          b = f2bf(v);
          htext[(size_t)row * 768 + col] = b;
        } else {
          v = fmaxf(v, 0.f) + bf2f(A[(size_t)row * K + col]);  // residual = acatPrev h-half
          b = f2bf(v);
        }
        aN[(size_t)row * 1536 + col] = b;   // h-half of [h|msg]
        hs[row_l * 192 + col_l] = b;
      }
    }
  }

  // ---- epilogue step 2 (runtime-gated): per-graph segment-sum -> msg-half (4 graphs/tile) ----
  if (esrc != nullptr){
    int* cnt            = (int*)((char*)LDS + 49152);            // [128]
    unsigned short* off = (unsigned short*)((char*)LDS + 49664); // [4][33]
    unsigned char* srt  = (unsigned char*)((char*)LDS + 49928);  // [4][64]
    int* wcur           = (int*)((char*)LDS + 50188);            // [128]
    if (t < 128) cnt[t] = 0;
    __syncthreads();
    const int g = t >> 6;                   // 4 graphs x 64 edges = 256 threads
    const int ge = (by*4 + g)*64 + (t & 63);
    const int es = esrc[ge] & 31, et = etgt[ge] & 31;   // intra-graph local ids
    atomicAdd(&cnt[g*32 + et], 1);
    __syncthreads();
    if (t < 4){
      int o = 0;
      for (int n2 = 0; n2 < 32; ++n2){
        off[t*33 + n2] = (unsigned short)o;
        wcur[t*32 + n2] = o;
        o += cnt[t*32 + n2];
      }
      off[t*33 + 32] = (unsigned short)o;
    }
    __syncthreads();
    {
      const int slot = atomicAdd(&wcur[g*32 + et], 1);
      srt[g*64 + slot] = (unsigned char)es;
    }
    __syncthreads();
    // wave w handles (graph,node) pairs w, w+4, ...; lane covers 3 cols {lane, +64, +128}
    for (int pp = w; pp < 128; pp += 4){
      const int gg = pp >> 5, n2 = pp & 31;
      const int o0 = off[gg*33 + n2], o1 = off[gg*33 + n2 + 1];
      float s0 = 0.f, s1 = 0.f, s2 = 0.f;
      for (int k2 = o0; k2 < o1; ++k2){
        const unsigned short* r = hs + (gg*32 + (int)srt[gg*64 + k2]) * 192;
        s0 += bf2f(r[lane]); s1 += bf2f(r[lane + 64]); s2 += bf2f(r[lane + 128]);
      }
      unsigned short* o = aN + (size_t)(brow + pp) * 1536 + 768 + bcol;
      o[lane]       = f2bf(s0);
      o[lane + 64]  = f2bf(s1);
      o[lane + 128] = f2bf(s2);
    }
  }
}

// ================= 128x128 m97-style GEMM (z_teacher only) =================
// EPI 2: z = relu(acc + bias) -> obf at col base 3840, stride 4608 (edge_repr)
template<int EPI>
__global__ __launch_bounds__(256) void k_gemm(
    const unsigned short* __restrict__ A, const unsigned short* __restrict__ Bt, int K,
    const float* __restrict__ bias,
    unsigned short* __restrict__ obf, float* __restrict__ of32)
{
  __shared__ unsigned short As[128*64];
  __shared__ unsigned short Bs[128*64];
  const int t = threadIdx.x;
  const int lane = t & 63, wave = t >> 6;

  const int bid = blockIdx.x;
  const int cpx = gridDim.x >> 3;
  const int wg = (bid & 7) * cpx + (bid >> 3);
  const int by = wg / 6;
  const int bx = wg - by * 6;
  const int brow = by * 128;
  const int bcol = bx * 128;

  const int wr = (wave >> 1) * 64, wc = (wave & 1) * 64;

  f32x4 acc[4][4];
  #pragma unroll
  for (int m = 0; m < 4; ++m)
    #pragma unroll
    for (int n = 0; n < 4; ++n)
      acc[m][n] = f32x4{0.f, 0.f, 0.f, 0.f};

  const int srow = wave * 8 + (lane >> 3);
  const int scol = (lane & 7) * 8;
  const int nkt = K >> 6;

  const unsigned short* a0 = A  + (size_t)(brow + srow) * K + scol;
  const unsigned short* b0 = Bt + (size_t)(bcol + srow) * K + scol;
  unsigned short* asdst = As + wave * 512;
  unsigned short* bsdst = Bs + wave * 512;

  for (int kt = 0; kt < nkt; ++kt){
    const unsigned short* ak = a0 + kt * 64;
    const unsigned short* bk = b0 + kt * 64;
    #pragma unroll
    for (int i = 0; i < 4; ++i)
      gld_lds16(ak + (size_t)i * 32 * K, asdst + i * 2048);
    #pragma unroll
    for (int i = 0; i < 4; ++i)
      gld_lds16(bk + (size_t)i * 32 * K, bsdst + i * 2048);
    __syncthreads();

    #pragma unroll
    for (int ks = 0; ks < 2; ++ks){
      bf16x8 af[4], bfr[4];
      const int kb = ks * 64 + ((lane >> 4) * 16);
      #pragma unroll
      for (int m = 0; m < 4; ++m)
        af[m] = *(const bf16x8*)((const char*)As + (wr + m * 16 + (lane & 15)) * 128 + kb);
      #pragma unroll
      for (int n = 0; n < 4; ++n)
        bfr[n] = *(const bf16x8*)((const char*)Bs + (wc + n * 16 + (lane & 15)) * 128 + kb);
      #pragma unroll
      for (int m = 0; m < 4; ++m)
        #pragma unroll
        for (int n = 0; n < 4; ++n)
          acc[m][n] = __builtin_amdgcn_mfma_f32_16x16x32_bf16(af[m], bfr[n], acc[m][n], 0, 0, 0);
    }
    __syncthreads();
  }

  #pragma unroll
  for (int m = 0; m < 4; ++m){
    #pragma unroll
    for (int n = 0; n < 4; ++n){
      int col = bcol + wc + n * 16 + (lane & 15);
      #pragma unroll
      for (int j = 0; j < 4; ++j){
        int row = brow + wr + m * 16 + ((lane >> 4) * 4) + j;
        float v = acc[m][n][j];
        if (EPI == 2){
          v = fmaxf(v + bias[col], 0.f);
          obf[(size_t)row * 4608 + 3840 + col] = f2bf(v);
        } else {
          v = fmaxf(v + bias[col], 0.f);
          of32[(size_t)row * 768 + col] = v;
        }
      }
    }
  }
}

// ================= split-K GEMM for hid: erepr(1024x4608) @ Wp1T -> hidp[8][1024][768] =================
// Grid 384 = 48 tiles x 8 K-slices (slice = 9 K-tiles = 576). Plain stores to
// per-slice partial buffers (deterministic, no zero-init needed); k_logits reduces.
__global__ __launch_bounds__(256) void k_gemmsk(
    const unsigned short* __restrict__ A, const unsigned short* __restrict__ Bt,
    float* __restrict__ hidp)
{
  const int K = KP1;
  __shared__ unsigned short As[128*64];
  __shared__ unsigned short Bs[128*64];
  const int t = threadIdx.x;
  const int lane = t & 63, wave = t >> 6;

  const int bid = blockIdx.x;
  const int cpx = gridDim.x >> 3;               // 48
  const int wg = (bid & 7) * cpx + (bid >> 3);  // XCD-chunked, bijective (384%8==0)
  const int ksl = wg / 48;                      // K-slice 0..7
  const int tile = wg - ksl * 48;
  const int by = tile / 6, bx = tile - (tile / 6) * 6;
  const int brow = by * 128, bcol = bx * 128;

  const int wr = (wave >> 1) * 64, wc = (wave & 1) * 64;

  f32x4 acc[4][4];
  #pragma unroll
  for (int m = 0; m < 4; ++m)
    #pragma unroll
    for (int n = 0; n < 4; ++n)
      acc[m][n] = f32x4{0.f, 0.f, 0.f, 0.f};

  const int srow = wave * 8 + (lane >> 3);
  const int scol = (lane & 7) * 8;

  const unsigned short* a0 = A  + (size_t)(brow + srow) * K + scol;
  const unsigned short* b0 = Bt + (size_t)(bcol + srow) * K + scol;
  unsigned short* asdst = As + wave * 512;
  unsigned short* bsdst = Bs + wave * 512;

  const int kt0 = ksl * 9, kt1 = kt0 + 9;
  for (int kt = kt0; kt < kt1; ++kt){
    const unsigned short* ak = a0 + kt * 64;
    const unsigned short* bk = b0 + kt * 64;
    #pragma unroll
    for (int i = 0; i < 4; ++i)
      gld_lds16(ak + (size_t)i * 32 * K, asdst + i * 2048);
    #pragma unroll
    for (int i = 0; i < 4; ++i)
      gld_lds16(bk + (size_t)i * 32 * K, bsdst + i * 2048);
    __syncthreads();

    #pragma unroll
    for (int ks = 0; ks < 2; ++ks){
      bf16x8 af[4], bfr[4];
      const int kb = ks * 64 + ((lane >> 4) * 16);
      #pragma unroll
      for (int m = 0; m < 4; ++m)
        af[m] = *(const bf16x8*)((const char*)As + (wr + m * 16 + (lane & 15)) * 128 + kb);
      #pragma unroll
      for (int n = 0; n < 4; ++n)
        bfr[n] = *(const bf16x8*)((const char*)Bs + (wc + n * 16 + (lane & 15)) * 128 + kb);
      #pragma unroll
      for (int m = 0; m < 4; ++m)
        #pragma unroll
        for (int n = 0; n < 4; ++n)
          acc[m][n] = __builtin_amdgcn_mfma_f32_16x16x32_bf16(af[m], bfr[n], acc[m][n], 0, 0, 0);
    }
    __syncthreads();
  }

  float* out = hidp + (size_t)ksl * BB * HH;
  #pragma unroll
  for (int m = 0; m < 4; ++m){
    #pragma unroll
    for (int n = 0; n < 4; ++n){
      int col = bcol + wc + n * 16 + (lane & 15);
      #pragma unroll
      for (int j = 0; j < 4; ++j){
        int row = brow + wr + m * 16 + ((lane >> 4) * 4) + j;
        out[(size_t)row * 768 + col] = acc[m][n][j];
      }
    }
  }
}

// ---------------- per-graph: dist + gather h_c/h_t/h_dist into edge_repr
// h lives in acat's h-half (stride 1536).
__global__ __launch_bounds__(256) void k_build(const unsigned short* __restrict__ acatH,
                                               const unsigned short* __restrict__ htext,
                                               const int* __restrict__ tni,
                                               const int* __restrict__ esrc,
                                               const int* __restrict__ etgt,
                                               const float* __restrict__ dist_emb,
                                               unsigned short* __restrict__ er){
  int g = blockIdx.x;
  int t = threadIdx.x;
  __shared__ int s_dist;
  int c = tni[g * 2 + 0], tt = tni[g * 2 + 1];
  if (t == 0){
    // reference quirk: first_edge indexed with LOCAL node ids -> graph 0's edges only
    int cu = c, tu = tt;
    for (int e = 0; e < 64; ++e){ if (esrc[e] == c){ cu = etgt[e]; break; } }
    for (int e = 0; e < 64; ++e){ if (esrc[e] == tt){ tu = etgt[e]; break; } }
    int d = cu - tu; if (d < 0) d = -d; if (d > 31) d = 31;
    s_dist = d;
  }
  __syncthreads();
  size_t rc = (size_t)(g * 32 + c) * 1536, rt = (size_t)(g * 32 + tt) * 1536;
  size_t rc8 = (size_t)(g * 32 + c) * 768, rt8 = (size_t)(g * 32 + tt) * 768;
  unsigned short* o = er + (size_t)g * 4608;
  int d = s_dist;
  for (int i = t; i < 768; i += 256){
    o[i]        = acatH[rc + i];
    o[768 + i]  = htext[rc8 + i];
    o[1536 + i] = acatH[rt + i];
    o[2304 + i] = htext[rt8 + i];
    o[3072 + i] = f2bf(dist_emb[(size_t)d * 768 + i]);
  }
}

// ---------------- logits: out[i] = relu(sum_p hidp[p][i,:] + b_p1) . W_p2 + b_p2
__global__ __launch_bounds__(256) void k_logits(const float* __restrict__ hidp,
                                                const float* __restrict__ bp1,
                                                const float* __restrict__ wp2,
                                                const float* __restrict__ bp2,
                                                float* __restrict__ out){
  int row = blockIdx.x * 4 + (threadIdx.x >> 6);
  int lane = threadIdx.x & 63;
  float s = 0.f;
  for (int j = lane; j < 768; j += 64){
    float v = 0.f;
    #pragma unroll
    for (int p = 0; p < 8; ++p)
      v += hidp[(size_t)p * BB * HH + (size_t)row * 768 + j];
    v = fmaxf(v + bp1[j], 0.f);
    s += v * wp2[j];
  }
  #pragma unroll
  for (int off = 32; off; off >>= 1) s += __shfl_down(s, off);
  if (lane == 0) out[row] = s + bp2[0];
}

extern "C" void kernel_launch(void* const* d_in, const int* in_sizes, int n_in,
                              void* d_out, int out_size, void* d_ws, size_t ws_size,
                              hipStream_t stream){
  const float* x        = (const float*)d_in[0];
  const int*   sid      = (const int*)d_in[1];
  const int*   eid      = (const int*)d_in[2];
  const int*   esrc     = (const int*)d_in[3];
  const int*   etgt     = esrc + EE;
  const int*   tni      = (const int*)d_in[4];
  const float* expl     = (const float*)d_in[5];
  const float* W_sem    = (const float*)d_in[6];
  const float* spk      = (const float*)d_in[7];
  const float* emo      = (const float*)d_in[8];
  const float* w_self   = (const float*)d_in[9];
  const float* w_nbr    = (const float*)d_in[10];
  const float* dist_emb = (const float*)d_in[11];
  const float* W_expl   = (const float*)d_in[12];
  const float* b_expl   = (const float*)d_in[13];
  const float* W_p1     = (const float*)d_in[14];
  const float* b_p1     = (const float*)d_in[15];
  const float* W_p2     = (const float*)d_in[16];
  const float* b_p2     = (const float*)d_in[17];

  char* ws = (char*)d_ws;
  size_t off = 0;
  auto alloc = [&](size_t bytes) -> void* {
    void* p = ws + off; off += (bytes + 255) & ~(size_t)255; return p;
  };
  unsigned short* acat0 = (unsigned short*)alloc((size_t)NN * KCAT * 2);
  unsigned short* acat1 = (unsigned short*)alloc((size_t)NN * KCAT * 2);
  unsigned short* xbf   = (unsigned short*)alloc((size_t)NN * KSEM * 2);
  unsigned short* htext = (unsigned short*)alloc((size_t)NN * HH * 2);
  unsigned short* WsemT = (unsigned short*)alloc((size_t)HH * KSEM * 2);
  unsigned short* WcatT = (unsigned short*)alloc((size_t)3 * HH * KCAT * 2);
  unsigned short* WexplT= (unsigned short*)alloc((size_t)HH * HH * 2);
  unsigned short* Wp1T  = (unsigned short*)alloc((size_t)HH * KP1 * 2);
  unsigned short* erepr = (unsigned short*)alloc((size_t)BB * KP1 * 2);
  float*          hidp  = (float*)alloc((size_t)8 * BB * HH * 4);
  unsigned short* explbf= (unsigned short*)alloc((size_t)BB * HH * 2);
  (void)ws_size; (void)in_sizes; (void)n_in; (void)out_size;

  // weight transposes (f32 -> bf16, [K][768] -> [768][K])
  k_transpose<<<dim3(KSEM/32, 24), 256, 0, stream>>>(W_sem, WsemT, KSEM, KSEM, 0);
  for (int l = 0; l < 3; ++l){
    k_transpose<<<dim3(24, 24), 256, 0, stream>>>(w_self + (size_t)l*HH*HH, WcatT + (size_t)l*HH*KCAT, HH, KCAT, 0);
    k_transpose<<<dim3(24, 24), 256, 0, stream>>>(w_nbr  + (size_t)l*HH*HH, WcatT + (size_t)l*HH*KCAT, HH, KCAT, HH);
  }
  k_transpose<<<dim3(24, 24), 256, 0, stream>>>(W_expl, WexplT, HH, HH, 0);
  k_transpose<<<dim3(KP1/32, 24), 256, 0, stream>>>(W_p1, Wp1T, KP1, KP1, 0);

  // activation casts f32 -> bf16
  k_cast<<<(NN*KSEM/8 + 255)/256, 256, 0, stream>>>(x, xbf, NN*KSEM/8);
  k_cast<<<(BB*HH/8 + 255)/256, 256, 0, stream>>>(expl, explbf, BB*HH/8);

  // h_text = relu(x @ W_sem + spk + emo) -> acat0 [h|msg] + htext  [128x192, 2 blocks/CU]
  k_gemm8<0><<<4*(NN/128), 256, 0, stream>>>(xbf, WsemT, KSEM,
      acat0, htext, sid, eid, spk, emo, esrc, etgt);

  // GNN layers, msg fused into epilogue; ping-pong acat buffers
  k_gemm8<1><<<4*(NN/128), 256, 0, stream>>>(acat0, WcatT + (size_t)0*HH*KCAT, KCAT,
      acat1, nullptr, nullptr, nullptr, nullptr, nullptr, esrc, etgt);
  k_gemm8<1><<<4*(NN/128), 256, 0, stream>>>(acat1, WcatT + (size_t)1*HH*KCAT, KCAT,
      acat0, nullptr, nullptr, nullptr, nullptr, nullptr, esrc, etgt);
  k_gemm8<1><<<4*(NN/128), 256, 0, stream>>>(acat0, WcatT + (size_t)2*HH*KCAT, KCAT,
      acat1, nullptr, nullptr, nullptr, nullptr, nullptr, nullptr, nullptr);  // msg skipped

  // z_teacher into edge_repr cols [3840,4608)  [128^2]
  k_gemm<2><<<6*(BB/128), 256, 0, stream>>>(explbf, WexplT, HH, b_expl, erepr, nullptr);

  // gather h_c/h_t/h_dist into edge_repr cols [0,3840); final h = acat1 h-half
  k_build<<<BB, 256, 0, stream>>>(acat1, htext, tni, esrc, etgt, dist_emb, erepr);

  // hid partials = erepr @ W_p1 (split-K 8, 384 blocks)
  k_gemmsk<<<384, 256, 0, stream>>>(erepr, Wp1T, hidp);

  // logits (fused split-K reduce + bias + relu + projection)
  k_logits<<<BB/4, 256, 0, stream>>>(hidp, b_p1, W_p2, b_p2, (float*)d_out);
}